// Round 1
// baseline (4473.143 us; speedup 1.0000x reference)
//
#include <hip/hip_runtime.h>
#include <hip/hip_bf16.h>
#include <math.h>

// ---------------------------------------------------------------------------
// RobustDecoder: conv stem -> 4x selective-SSM (Mamba) layers -> pool -> heads
// Round 1: correctness-first full fp32 pipeline.
// ---------------------------------------------------------------------------

#define D_MODEL 256
#define D_INNER 512
#define D_STATE 16
#define DT_RANK 16
#define N_LAYERS 4
#define N_DEPTHS 4
#define N_EMB 8192
#define BATCH 8
#define SEQ 1024   // 32*32

// ---------------------------------------------------------------------------
// conv1: (8,3,128,128) -> (8,128,64,64), 3x3 stride2 pad1, + bias
// ---------------------------------------------------------------------------
__global__ __launch_bounds__(256) void conv1_k(const float* __restrict__ x,
                                               const float* __restrict__ w,
                                               const float* __restrict__ b,
                                               float* __restrict__ out) {
    int idx = blockIdx.x * 256 + threadIdx.x;
    if (idx >= 8 * 128 * 64 * 64) return;
    int ow = idx & 63;
    int oh = (idx >> 6) & 63;
    int oc = (idx >> 12) & 127;
    int bb = idx >> 19;
    float acc = b[oc];
    int ih0 = oh * 2 - 1, iw0 = ow * 2 - 1;
    for (int ic = 0; ic < 3; ++ic) {
        const float* xp = x + ((size_t)(bb * 3 + ic)) * 128 * 128;
        const float* wp = w + ((oc * 3 + ic) * 9);
#pragma unroll
        for (int r = 0; r < 3; ++r) {
            int ih = ih0 + r;
            if ((unsigned)ih < 128u) {
#pragma unroll
                for (int c = 0; c < 3; ++c) {
                    int iw = iw0 + c;
                    if ((unsigned)iw < 128u)
                        acc = fmaf(xp[ih * 128 + iw], wp[r * 3 + c], acc);
                }
            }
        }
    }
    out[idx] = acc;
}

// ---------------------------------------------------------------------------
// conv2: (8,128,64,64) -> (8,256,32,32), 3x3 stride2 pad1, + bias
// thread computes 4 consecutive oc to amortize input loads
// ---------------------------------------------------------------------------
__global__ __launch_bounds__(256) void conv2_k(const float* __restrict__ x,
                                               const float* __restrict__ w,
                                               const float* __restrict__ bsc,
                                               float* __restrict__ out) {
    int idx = blockIdx.x * 256 + threadIdx.x;  // 8*64*32*32 = 524288
    if (idx >= 8 * 64 * 32 * 32) return;
    int ow = idx & 31;
    int oh = (idx >> 5) & 31;
    int ocq = (idx >> 10) & 63;
    int bb = idx >> 16;
    int oc0 = ocq * 4;
    float acc0 = bsc[oc0], acc1 = bsc[oc0 + 1], acc2 = bsc[oc0 + 2], acc3 = bsc[oc0 + 3];
    int ih0 = oh * 2 - 1, iw0 = ow * 2 - 1;
    for (int ic = 0; ic < 128; ++ic) {
        const float* xp = x + ((size_t)(bb * 128 + ic)) * 4096;
        float in[9];
#pragma unroll
        for (int r = 0; r < 3; ++r) {
            int ih = ih0 + r;
#pragma unroll
            for (int c = 0; c < 3; ++c) {
                int iw = iw0 + c;
                in[r * 3 + c] = ((unsigned)ih < 64u && (unsigned)iw < 64u) ? xp[ih * 64 + iw] : 0.f;
            }
        }
        const float* wp = w + ((size_t)oc0 * 128 + ic) * 9;
#pragma unroll
        for (int k = 0; k < 9; ++k) {
            acc0 = fmaf(in[k], wp[k], acc0);
            acc1 = fmaf(in[k], wp[1152 + k], acc1);
            acc2 = fmaf(in[k], wp[2304 + k], acc2);
            acc3 = fmaf(in[k], wp[3456 + k], acc3);
        }
    }
    size_t ob = ((size_t)(bb * 256 + oc0) * 32 + oh) * 32 + ow;
    out[ob] = acc0;
    out[ob + 1024] = acc1;
    out[ob + 2048] = acc2;
    out[ob + 3072] = acc3;
}

// ---------------------------------------------------------------------------
// GroupNorm stats: one block per (batch, group). Channels in a group are
// contiguous, so the group region is contiguous: cpg*HW floats.
// ---------------------------------------------------------------------------
__global__ __launch_bounds__(256) void gn_stats_k(const float* __restrict__ x,
                                                  float* __restrict__ stats,
                                                  int cpg, int HW) {
    int bg = blockIdx.x;
    const float* xp = x + (size_t)bg * cpg * HW;
    int n = cpg * HW;
    float s = 0.f, ss = 0.f;
    for (int i = threadIdx.x; i < n; i += 256) {
        float v = xp[i];
        s += v;
        ss += v * v;
    }
#pragma unroll
    for (int o = 32; o > 0; o >>= 1) {
        s += __shfl_down(s, o);
        ss += __shfl_down(ss, o);
    }
    __shared__ float sh[4], sh2[4];
    int lane = threadIdx.x & 63, wid = threadIdx.x >> 6;
    if (lane == 0) { sh[wid] = s; sh2[wid] = ss; }
    __syncthreads();
    if (threadIdx.x == 0) {
        float S = sh[0] + sh[1] + sh[2] + sh[3];
        float SS = sh2[0] + sh2[1] + sh2[2] + sh2[3];
        float mean = S / n;
        float var = SS / n - mean * mean;
        stats[bg * 2] = mean;
        stats[bg * 2 + 1] = rsqrtf(var + 1e-5f);
    }
}

// ---------------------------------------------------------------------------
// GroupNorm apply + SiLU (in place)
// ---------------------------------------------------------------------------
__global__ __launch_bounds__(256) void gn_apply_k(float* __restrict__ x,
                                                  const float* __restrict__ stats,
                                                  const float* __restrict__ g,
                                                  const float* __restrict__ b,
                                                  int C, int cpg, int HW, int total) {
    int idx = blockIdx.x * 256 + threadIdx.x;
    if (idx >= total) return;
    int ch = (idx / HW) % C;
    int bb = idx / (HW * C);
    int grp = ch / cpg;
    int bg = bb * (C / cpg) + grp;
    float mean = stats[bg * 2], rstd = stats[bg * 2 + 1];
    float v = (x[idx] - mean) * rstd * g[ch] + b[ch];
    x[idx] = v / (1.f + __expf(-v));  // SiLU
}

// ---------------------------------------------------------------------------
// transpose (B,C,L) -> (B,L,C)
// ---------------------------------------------------------------------------
__global__ __launch_bounds__(256) void transpose_k(const float* __restrict__ h2,
                                                   float* __restrict__ f) {
    int idx = blockIdx.x * 256 + threadIdx.x;  // 8*1024*256
    if (idx >= 8 * 1024 * 256) return;
    int c = idx & 255;
    int l = (idx >> 8) & 1023;
    int b = idx >> 18;
    f[idx] = h2[((size_t)b * 256 + c) * 1024 + l];
}

// ---------------------------------------------------------------------------
// LayerNorm over last dim 256. One wave per row (4 rows / block).
// ---------------------------------------------------------------------------
__global__ __launch_bounds__(256) void ln_k(const float* __restrict__ f,
                                            const float* __restrict__ g,
                                            const float* __restrict__ b,
                                            float* __restrict__ xn) {
    int row = blockIdx.x * 4 + (threadIdx.x >> 6);
    int lane = threadIdx.x & 63;
    const float* xp = f + (size_t)row * 256;
    float4 v = *(const float4*)(xp + lane * 4);
    float s = v.x + v.y + v.z + v.w;
#pragma unroll
    for (int o = 32; o > 0; o >>= 1) s += __shfl_xor(s, o);
    float mean = s * (1.f / 256.f);
    float dx = v.x - mean, dy = v.y - mean, dz = v.z - mean, dw = v.w - mean;
    float ss = dx * dx + dy * dy + dz * dz + dw * dw;
#pragma unroll
    for (int o = 32; o > 0; o >>= 1) ss += __shfl_xor(ss, o);
    float rstd = rsqrtf(ss * (1.f / 256.f) + 1e-5f);
    float4 gg = *(const float4*)(g + lane * 4);
    float4 bb = *(const float4*)(b + lane * 4);
    float4 o4;
    o4.x = dx * rstd * gg.x + bb.x;
    o4.y = dy * rstd * gg.y + bb.y;
    o4.z = dz * rstd * gg.z + bb.z;
    o4.w = dw * rstd * gg.w + bb.w;
    *(float4*)(xn + (size_t)row * 256 + lane * 4) = o4;
}

// ---------------------------------------------------------------------------
// Generic GEMM: C[M,N] = act(A[M,K] @ W[N,K]^T + bias) (optional += into C)
// A row stride = lda. W row stride = K. 64x64 tile, 4x4 per thread.
// Requires M % 64 == 0, K % 16 == 0 (true for all uses). N bounds-checked.
// ---------------------------------------------------------------------------
template <int BIAS, int ACT, int ACCUM>
__global__ __launch_bounds__(256) void gemm_tn(const float* __restrict__ A,
                                               const float* __restrict__ W,
                                               const float* __restrict__ bias,
                                               float* __restrict__ C,
                                               int M, int N, int K, int lda) {
    __shared__ float As[16][68];   // 68: keep float4 rows 16B-aligned
    __shared__ float Ws[16][68];
    const int t = threadIdx.x;
    const int tx = t & 15;
    const int ty = t >> 4;
    const int rowBase = blockIdx.y * 64;
    const int colBase = blockIdx.x * 64;
    const int lRow = t >> 2;
    const int lK = (t & 3) * 4;
    float acc[4][4] = {};
    for (int k0 = 0; k0 < K; k0 += 16) {
        {
            const float* src = A + (size_t)(rowBase + lRow) * lda + k0 + lK;
            float4 v = *(const float4*)src;
            As[lK + 0][lRow] = v.x;
            As[lK + 1][lRow] = v.y;
            As[lK + 2][lRow] = v.z;
            As[lK + 3][lRow] = v.w;
        }
        {
            int n = colBase + lRow;
            float4 v = make_float4(0.f, 0.f, 0.f, 0.f);
            if (n < N) v = *(const float4*)(W + (size_t)n * K + k0 + lK);
            Ws[lK + 0][lRow] = v.x;
            Ws[lK + 1][lRow] = v.y;
            Ws[lK + 2][lRow] = v.z;
            Ws[lK + 3][lRow] = v.w;
        }
        __syncthreads();
#pragma unroll
        for (int kk = 0; kk < 16; ++kk) {
            float4 a4 = *(const float4*)&As[kk][ty * 4];
            float4 w4 = *(const float4*)&Ws[kk][tx * 4];
            float av[4] = {a4.x, a4.y, a4.z, a4.w};
            float wv[4] = {w4.x, w4.y, w4.z, w4.w};
#pragma unroll
            for (int i = 0; i < 4; ++i)
#pragma unroll
                for (int j = 0; j < 4; ++j)
                    acc[i][j] = fmaf(av[i], wv[j], acc[i][j]);
        }
        __syncthreads();
    }
#pragma unroll
    for (int i = 0; i < 4; ++i) {
        int row = rowBase + ty * 4 + i;
#pragma unroll
        for (int j = 0; j < 4; ++j) {
            int col = colBase + tx * 4 + j;
            if (col < N) {
                float v = acc[i][j];
                if (BIAS) v += bias[col];
                if (ACT == 1) v = (v > 20.f) ? v : log1pf(__expf(v));  // softplus
                size_t idx = (size_t)row * N + col;
                if (ACCUM)
                    C[idx] += v;
                else
                    C[idx] = v;
            }
        }
    }
}

// ---------------------------------------------------------------------------
// Causal depthwise conv1d (k=4) over sequence + bias + SiLU
// in: xz (B, L, 1024) first 512 cols; out: xc (B, L, 512)
// ---------------------------------------------------------------------------
__global__ __launch_bounds__(256) void dwconv_k(const float* __restrict__ xz,
                                                const float* __restrict__ cw,
                                                const float* __restrict__ cb,
                                                float* __restrict__ xc) {
    int idx = blockIdx.x * 256 + threadIdx.x;  // 8*1024*512
    if (idx >= 8 * 1024 * 512) return;
    int d = idx & 511;
    int tt = (idx >> 9) & 1023;
    int b = idx >> 19;
    const float* xp = xz + (size_t)b * 1024 * 1024 + d;
    float w0 = cw[d * 4], w1 = cw[d * 4 + 1], w2 = cw[d * 4 + 2], w3 = cw[d * 4 + 3];
    float acc = cb[d];
    if (tt >= 3) acc = fmaf(xp[(size_t)(tt - 3) * 1024], w0, acc);
    if (tt >= 2) acc = fmaf(xp[(size_t)(tt - 2) * 1024], w1, acc);
    if (tt >= 1) acc = fmaf(xp[(size_t)(tt - 1) * 1024], w2, acc);
    acc = fmaf(xp[(size_t)tt * 1024], w3, acc);
    xc[idx] = acc / (1.f + __expf(-acc));  // SiLU
}

// ---------------------------------------------------------------------------
// Selective scan. Lane per (b, d, s): 16 lanes per (b,d) reduce via shfl_xor.
// Fused epilogue: y = (ssm_y + Dp*xc) * silu(z)
// ---------------------------------------------------------------------------
__global__ __launch_bounds__(256) void scan_k(const float* __restrict__ dtb,
                                              const float* __restrict__ xdbl,
                                              const float* __restrict__ xc,
                                              const float* __restrict__ A_log,
                                              const float* __restrict__ Dp,
                                              const float* __restrict__ xz,
                                              float* __restrict__ y) {
    int s = threadIdx.x & 15;
    int dl = threadIdx.x >> 4;          // 0..15
    int d = blockIdx.x * 16 + dl;       // 0..511
    int b = blockIdx.y;                 // 0..7
    float A = -__expf(A_log[d * 16 + s]);
    float Dpd = Dp[d];
    float h = 0.f;
    const float* dtp = dtb + (size_t)b * 1024 * 512 + d;
    const float* xcp = xc + (size_t)b * 1024 * 512 + d;
    const float* bcp = xdbl + (size_t)b * 1024 * 48;
    const float* zp = xz + (size_t)b * 1024 * 1024 + 512 + d;
    float* yp = y + (size_t)b * 1024 * 512 + d;
    for (int tt = 0; tt < 1024; ++tt) {
        float dt = dtp[(size_t)tt * 512];
        float xv = xcp[(size_t)tt * 512];
        float Bv = bcp[tt * 48 + 16 + s];
        float Cv = bcp[tt * 48 + 32 + s];
        float dA = __expf(dt * A);
        h = fmaf(dA, h, dt * xv * Bv);
        float p = h * Cv;
        p += __shfl_xor(p, 1);
        p += __shfl_xor(p, 2);
        p += __shfl_xor(p, 4);
        p += __shfl_xor(p, 8);
        if (s == 0) {
            float zv = zp[(size_t)tt * 1024];
            float sz = zv / (1.f + __expf(-zv));
            yp[(size_t)tt * 512] = (p + Dpd * xv) * sz;
        }
    }
}

// ---------------------------------------------------------------------------
// Adaptive avg-pool 32x32 -> 8x8 over sequence layout (B, L, C)
// feat[b, r*8+c, ch] = mean_{i,j in 4x4} f[b, (4r+i)*32 + 4c+j, ch]
// ---------------------------------------------------------------------------
__global__ __launch_bounds__(256) void pool_k(const float* __restrict__ f,
                                              float* __restrict__ feat) {
    int idx = blockIdx.x * 256 + threadIdx.x;  // 8*64*256
    if (idx >= 8 * 64 * 256) return;
    int ch = idx & 255;
    int rc = (idx >> 8) & 63;
    int b = idx >> 14;
    int r = rc >> 3, c = rc & 7;
    float s = 0.f;
#pragma unroll
    for (int i = 0; i < 4; ++i)
#pragma unroll
        for (int j = 0; j < 4; ++j) {
            int l = (r * 4 + i) * 32 + (c * 4 + j);
            s += f[((size_t)b * 1024 + l) * 256 + ch];
        }
    feat[idx] = s * (1.f / 16.f);
}

// ---------------------------------------------------------------------------
// launch
// ---------------------------------------------------------------------------
extern "C" void kernel_launch(void* const* d_in, const int* in_sizes, int n_in,
                              void* d_out, int out_size, void* d_ws, size_t ws_size,
                              hipStream_t stream) {
    const float* x = (const float*)d_in[0];
    const float* conv1_w = (const float*)d_in[1];
    const float* conv1_b = (const float*)d_in[2];
    const float* gn1_g = (const float*)d_in[3];
    const float* gn1_b = (const float*)d_in[4];
    const float* conv2_w = (const float*)d_in[5];
    const float* conv2_b = (const float*)d_in[6];
    const float* gn2_g = (const float*)d_in[7];
    const float* gn2_b = (const float*)d_in[8];
    const float* ln_g = (const float*)d_in[9];
    const float* ln_b = (const float*)d_in[10];
    const float* in_w = (const float*)d_in[11];
    const float* cw = (const float*)d_in[12];
    const float* cb = (const float*)d_in[13];
    const float* xp_w = (const float*)d_in[14];
    const float* dtp_w = (const float*)d_in[15];
    const float* dtp_b = (const float*)d_in[16];
    const float* A_log = (const float*)d_in[17];
    const float* Dp = (const float*)d_in[18];
    const float* out_w = (const float*)d_in[19];
    const float* head_w = (const float*)d_in[20];
    const float* head_b = (const float*)d_in[21];
    float* out = (float*)d_out;

    float* ws = (float*)d_ws;
    // workspace layout (floats)
    float* f = ws + 0;                 // 2,097,152
    float* xn = ws + 2097152;          // 2,097,152
    float* xz = ws + 4194304;          // 8,388,608
    float* xc = ws + 12582912;         // 4,194,304
    float* xdbl = ws + 16777216;       // 393,216
    float* dtb = ws + 17170432;        // 4,194,304
    float* ybuf = ws + 21364736;       // 4,194,304
    float* feat = ws + 25559040;       // 131,072
    float* stats = ws + 25690112;      // 128
    float* h1 = xz;                    // alias: conv stem phase only (4,194,304 <= 8,388,608)
    float* h2 = xc;                    // alias: conv stem phase only (2,097,152 <= 4,194,304)

    // ---- conv stem ----
    conv1_k<<<(8 * 128 * 64 * 64 + 255) / 256, 256, 0, stream>>>(x, conv1_w, conv1_b, h1);
    gn_stats_k<<<64, 256, 0, stream>>>(h1, stats, 16, 4096);
    gn_apply_k<<<(8 * 128 * 64 * 64 + 255) / 256, 256, 0, stream>>>(h1, stats, gn1_g, gn1_b, 128, 16, 4096, 8 * 128 * 64 * 64);
    conv2_k<<<(8 * 64 * 32 * 32 + 255) / 256, 256, 0, stream>>>(h1, conv2_w, conv2_b, h2);
    gn_stats_k<<<64, 256, 0, stream>>>(h2, stats, 32, 1024);
    gn_apply_k<<<(8 * 256 * 32 * 32 + 255) / 256, 256, 0, stream>>>(h2, stats, gn2_g, gn2_b, 256, 32, 1024, 8 * 256 * 32 * 32);
    transpose_k<<<8192, 256, 0, stream>>>(h2, f);

    // ---- SSM layers ----
    for (int i = 0; i < N_LAYERS; ++i) {
        ln_k<<<2048, 256, 0, stream>>>(f, ln_g + i * 256, ln_b + i * 256, xn);
        // xz = xn @ in_w^T : (8192,1024)
        gemm_tn<0, 0, 0><<<dim3(16, 128), 256, 0, stream>>>(
            xn, in_w + (size_t)i * 1024 * 256, nullptr, xz, 8192, 1024, 256, 256);
        dwconv_k<<<(8 * 1024 * 512 + 255) / 256, 256, 0, stream>>>(
            xz, cw + i * 512 * 4, cb + i * 512, xc);
        // x_dbl = xc @ xp_w^T : (8192,48)
        gemm_tn<0, 0, 0><<<dim3(1, 128), 256, 0, stream>>>(
            xc, xp_w + (size_t)i * 48 * 512, nullptr, xdbl, 8192, 48, 512, 512);
        // dt = softplus(x_dbl[:, :16] @ dtp_w^T + dtp_b) : (8192,512)
        gemm_tn<1, 1, 0><<<dim3(8, 128), 256, 0, stream>>>(
            xdbl, dtp_w + (size_t)i * 512 * 16, dtp_b + i * 512, dtb, 8192, 512, 16, 48);
        // selective scan + fused gating epilogue
        scan_k<<<dim3(32, 8), 256, 0, stream>>>(
            dtb, xdbl, xc, A_log + (size_t)i * 512 * 16, Dp + i * 512, xz, ybuf);
        // f += ybuf @ out_w^T : (8192,256)
        gemm_tn<0, 0, 1><<<dim3(4, 128), 256, 0, stream>>>(
            ybuf, out_w + (size_t)i * 256 * 512, nullptr, f, 8192, 256, 512, 512);
    }

    // ---- pool + heads ----
    pool_k<<<(8 * 64 * 256 + 255) / 256, 256, 0, stream>>>(f, feat);
    for (int d = 0; d < N_DEPTHS; ++d) {
        gemm_tn<1, 0, 0><<<dim3(128, 8), 256, 0, stream>>>(
            feat, head_w + (size_t)d * N_EMB * 256, head_b + (size_t)d * N_EMB,
            out + (size_t)d * BATCH * 64 * N_EMB, 512, N_EMB, 256, 256);
    }
}

// Round 2
// 1728.804 us; speedup vs baseline: 2.5874x; 2.5874x over previous
//
#include <hip/hip_runtime.h>
#include <hip/hip_bf16.h>
#include <math.h>

// ---------------------------------------------------------------------------
// RobustDecoder: conv stem -> 4x selective-SSM (Mamba) layers -> pool -> heads
// Round 2: rewrite selective scan with LDS tile double-buffering + wave-
// synchronous deferred reduction (was 66% of runtime at 12% occupancy).
// ---------------------------------------------------------------------------

#define D_MODEL 256
#define D_INNER 512
#define D_STATE 16
#define DT_RANK 16
#define N_LAYERS 4
#define N_DEPTHS 4
#define N_EMB 8192
#define BATCH 8
#define SEQ 1024   // 32*32

// ---------------------------------------------------------------------------
// conv1: (8,3,128,128) -> (8,128,64,64), 3x3 stride2 pad1, + bias
// ---------------------------------------------------------------------------
__global__ __launch_bounds__(256) void conv1_k(const float* __restrict__ x,
                                               const float* __restrict__ w,
                                               const float* __restrict__ b,
                                               float* __restrict__ out) {
    int idx = blockIdx.x * 256 + threadIdx.x;
    if (idx >= 8 * 128 * 64 * 64) return;
    int ow = idx & 63;
    int oh = (idx >> 6) & 63;
    int oc = (idx >> 12) & 127;
    int bb = idx >> 19;
    float acc = b[oc];
    int ih0 = oh * 2 - 1, iw0 = ow * 2 - 1;
    for (int ic = 0; ic < 3; ++ic) {
        const float* xp = x + ((size_t)(bb * 3 + ic)) * 128 * 128;
        const float* wp = w + ((oc * 3 + ic) * 9);
#pragma unroll
        for (int r = 0; r < 3; ++r) {
            int ih = ih0 + r;
            if ((unsigned)ih < 128u) {
#pragma unroll
                for (int c = 0; c < 3; ++c) {
                    int iw = iw0 + c;
                    if ((unsigned)iw < 128u)
                        acc = fmaf(xp[ih * 128 + iw], wp[r * 3 + c], acc);
                }
            }
        }
    }
    out[idx] = acc;
}

// ---------------------------------------------------------------------------
// conv2: (8,128,64,64) -> (8,256,32,32), 3x3 stride2 pad1, + bias
// ---------------------------------------------------------------------------
__global__ __launch_bounds__(256) void conv2_k(const float* __restrict__ x,
                                               const float* __restrict__ w,
                                               const float* __restrict__ bsc,
                                               float* __restrict__ out) {
    int idx = blockIdx.x * 256 + threadIdx.x;  // 8*64*32*32 = 524288
    if (idx >= 8 * 64 * 32 * 32) return;
    int ow = idx & 31;
    int oh = (idx >> 5) & 31;
    int ocq = (idx >> 10) & 63;
    int bb = idx >> 16;
    int oc0 = ocq * 4;
    float acc0 = bsc[oc0], acc1 = bsc[oc0 + 1], acc2 = bsc[oc0 + 2], acc3 = bsc[oc0 + 3];
    int ih0 = oh * 2 - 1, iw0 = ow * 2 - 1;
    for (int ic = 0; ic < 128; ++ic) {
        const float* xp = x + ((size_t)(bb * 128 + ic)) * 4096;
        float in[9];
#pragma unroll
        for (int r = 0; r < 3; ++r) {
            int ih = ih0 + r;
#pragma unroll
            for (int c = 0; c < 3; ++c) {
                int iw = iw0 + c;
                in[r * 3 + c] = ((unsigned)ih < 64u && (unsigned)iw < 64u) ? xp[ih * 64 + iw] : 0.f;
            }
        }
        const float* wp = w + ((size_t)oc0 * 128 + ic) * 9;
#pragma unroll
        for (int k = 0; k < 9; ++k) {
            acc0 = fmaf(in[k], wp[k], acc0);
            acc1 = fmaf(in[k], wp[1152 + k], acc1);
            acc2 = fmaf(in[k], wp[2304 + k], acc2);
            acc3 = fmaf(in[k], wp[3456 + k], acc3);
        }
    }
    size_t ob = ((size_t)(bb * 256 + oc0) * 32 + oh) * 32 + ow;
    out[ob] = acc0;
    out[ob + 1024] = acc1;
    out[ob + 2048] = acc2;
    out[ob + 3072] = acc3;
}

// ---------------------------------------------------------------------------
// GroupNorm stats: one block per (batch, group).
// ---------------------------------------------------------------------------
__global__ __launch_bounds__(256) void gn_stats_k(const float* __restrict__ x,
                                                  float* __restrict__ stats,
                                                  int cpg, int HW) {
    int bg = blockIdx.x;
    const float* xp = x + (size_t)bg * cpg * HW;
    int n = cpg * HW;
    float s = 0.f, ss = 0.f;
    for (int i = threadIdx.x; i < n; i += 256) {
        float v = xp[i];
        s += v;
        ss += v * v;
    }
#pragma unroll
    for (int o = 32; o > 0; o >>= 1) {
        s += __shfl_down(s, o);
        ss += __shfl_down(ss, o);
    }
    __shared__ float sh[4], sh2[4];
    int lane = threadIdx.x & 63, wid = threadIdx.x >> 6;
    if (lane == 0) { sh[wid] = s; sh2[wid] = ss; }
    __syncthreads();
    if (threadIdx.x == 0) {
        float S = sh[0] + sh[1] + sh[2] + sh[3];
        float SS = sh2[0] + sh2[1] + sh2[2] + sh2[3];
        float mean = S / n;
        float var = SS / n - mean * mean;
        stats[bg * 2] = mean;
        stats[bg * 2 + 1] = rsqrtf(var + 1e-5f);
    }
}

// ---------------------------------------------------------------------------
// GroupNorm apply + SiLU (in place)
// ---------------------------------------------------------------------------
__global__ __launch_bounds__(256) void gn_apply_k(float* __restrict__ x,
                                                  const float* __restrict__ stats,
                                                  const float* __restrict__ g,
                                                  const float* __restrict__ b,
                                                  int C, int cpg, int HW, int total) {
    int idx = blockIdx.x * 256 + threadIdx.x;
    if (idx >= total) return;
    int ch = (idx / HW) % C;
    int bb = idx / (HW * C);
    int grp = ch / cpg;
    int bg = bb * (C / cpg) + grp;
    float mean = stats[bg * 2], rstd = stats[bg * 2 + 1];
    float v = (x[idx] - mean) * rstd * g[ch] + b[ch];
    x[idx] = v / (1.f + __expf(-v));  // SiLU
}

// ---------------------------------------------------------------------------
// transpose (B,C,L) -> (B,L,C)
// ---------------------------------------------------------------------------
__global__ __launch_bounds__(256) void transpose_k(const float* __restrict__ h2,
                                                   float* __restrict__ f) {
    int idx = blockIdx.x * 256 + threadIdx.x;  // 8*1024*256
    if (idx >= 8 * 1024 * 256) return;
    int c = idx & 255;
    int l = (idx >> 8) & 1023;
    int b = idx >> 18;
    f[idx] = h2[((size_t)b * 256 + c) * 1024 + l];
}

// ---------------------------------------------------------------------------
// LayerNorm over last dim 256. One wave per row (4 rows / block).
// ---------------------------------------------------------------------------
__global__ __launch_bounds__(256) void ln_k(const float* __restrict__ f,
                                            const float* __restrict__ g,
                                            const float* __restrict__ b,
                                            float* __restrict__ xn) {
    int row = blockIdx.x * 4 + (threadIdx.x >> 6);
    int lane = threadIdx.x & 63;
    const float* xp = f + (size_t)row * 256;
    float4 v = *(const float4*)(xp + lane * 4);
    float s = v.x + v.y + v.z + v.w;
#pragma unroll
    for (int o = 32; o > 0; o >>= 1) s += __shfl_xor(s, o);
    float mean = s * (1.f / 256.f);
    float dx = v.x - mean, dy = v.y - mean, dz = v.z - mean, dw = v.w - mean;
    float ss = dx * dx + dy * dy + dz * dz + dw * dw;
#pragma unroll
    for (int o = 32; o > 0; o >>= 1) ss += __shfl_xor(ss, o);
    float rstd = rsqrtf(ss * (1.f / 256.f) + 1e-5f);
    float4 gg = *(const float4*)(g + lane * 4);
    float4 bb = *(const float4*)(b + lane * 4);
    float4 o4;
    o4.x = dx * rstd * gg.x + bb.x;
    o4.y = dy * rstd * gg.y + bb.y;
    o4.z = dz * rstd * gg.z + bb.z;
    o4.w = dw * rstd * gg.w + bb.w;
    *(float4*)(xn + (size_t)row * 256 + lane * 4) = o4;
}

// ---------------------------------------------------------------------------
// Generic GEMM: C[M,N] = act(A[M,K] @ W[N,K]^T + bias) (optional += into C)
// ---------------------------------------------------------------------------
template <int BIAS, int ACT, int ACCUM>
__global__ __launch_bounds__(256) void gemm_tn(const float* __restrict__ A,
                                               const float* __restrict__ W,
                                               const float* __restrict__ bias,
                                               float* __restrict__ C,
                                               int M, int N, int K, int lda) {
    __shared__ float As[16][68];
    __shared__ float Ws[16][68];
    const int t = threadIdx.x;
    const int tx = t & 15;
    const int ty = t >> 4;
    const int rowBase = blockIdx.y * 64;
    const int colBase = blockIdx.x * 64;
    const int lRow = t >> 2;
    const int lK = (t & 3) * 4;
    float acc[4][4] = {};
    for (int k0 = 0; k0 < K; k0 += 16) {
        {
            const float* src = A + (size_t)(rowBase + lRow) * lda + k0 + lK;
            float4 v = *(const float4*)src;
            As[lK + 0][lRow] = v.x;
            As[lK + 1][lRow] = v.y;
            As[lK + 2][lRow] = v.z;
            As[lK + 3][lRow] = v.w;
        }
        {
            int n = colBase + lRow;
            float4 v = make_float4(0.f, 0.f, 0.f, 0.f);
            if (n < N) v = *(const float4*)(W + (size_t)n * K + k0 + lK);
            Ws[lK + 0][lRow] = v.x;
            Ws[lK + 1][lRow] = v.y;
            Ws[lK + 2][lRow] = v.z;
            Ws[lK + 3][lRow] = v.w;
        }
        __syncthreads();
#pragma unroll
        for (int kk = 0; kk < 16; ++kk) {
            float4 a4 = *(const float4*)&As[kk][ty * 4];
            float4 w4 = *(const float4*)&Ws[kk][tx * 4];
            float av[4] = {a4.x, a4.y, a4.z, a4.w};
            float wv[4] = {w4.x, w4.y, w4.z, w4.w};
#pragma unroll
            for (int i = 0; i < 4; ++i)
#pragma unroll
                for (int j = 0; j < 4; ++j)
                    acc[i][j] = fmaf(av[i], wv[j], acc[i][j]);
        }
        __syncthreads();
    }
#pragma unroll
    for (int i = 0; i < 4; ++i) {
        int row = rowBase + ty * 4 + i;
#pragma unroll
        for (int j = 0; j < 4; ++j) {
            int col = colBase + tx * 4 + j;
            if (col < N) {
                float v = acc[i][j];
                if (BIAS) v += bias[col];
                if (ACT == 1) v = (v > 20.f) ? v : log1pf(__expf(v));  // softplus
                size_t idx = (size_t)row * N + col;
                if (ACCUM)
                    C[idx] += v;
                else
                    C[idx] = v;
            }
        }
    }
}

// ---------------------------------------------------------------------------
// Causal depthwise conv1d (k=4) over sequence + bias + SiLU
// ---------------------------------------------------------------------------
__global__ __launch_bounds__(256) void dwconv_k(const float* __restrict__ xz,
                                                const float* __restrict__ cw,
                                                const float* __restrict__ cb,
                                                float* __restrict__ xc) {
    int idx = blockIdx.x * 256 + threadIdx.x;  // 8*1024*512
    if (idx >= 8 * 1024 * 512) return;
    int d = idx & 511;
    int tt = (idx >> 9) & 1023;
    int b = idx >> 19;
    const float* xp = xz + (size_t)b * 1024 * 1024 + d;
    float w0 = cw[d * 4], w1 = cw[d * 4 + 1], w2 = cw[d * 4 + 2], w3 = cw[d * 4 + 3];
    float acc = cb[d];
    if (tt >= 3) acc = fmaf(xp[(size_t)(tt - 3) * 1024], w0, acc);
    if (tt >= 2) acc = fmaf(xp[(size_t)(tt - 2) * 1024], w1, acc);
    if (tt >= 1) acc = fmaf(xp[(size_t)(tt - 1) * 1024], w2, acc);
    acc = fmaf(xp[(size_t)tt * 1024], w3, acc);
    xc[idx] = acc / (1.f + __expf(-acc));  // SiLU
}

// ---------------------------------------------------------------------------
// Selective scan v2. Block = (d-chunk of 16) x (batch). 256 threads:
// compute mapping (dl = tid>>4 channel, s = tid&15 state).
// - 64-step tiles of {dt, x, B, C, z} staged in LDS, double-buffered;
//   global float4 loads for tile t+1 issued before computing tile t.
// - per step: h = exp(dt*A)*h + dt*x*B (the only loop-carried chain);
//   p = h*C deferred to LDS; every 16 steps each wave reduces its own
//   LDS region wave-synchronously (no __syncthreads needed within a wave).
// - fused epilogue y = (sum_s p + Dp*x) * silu(z).
// ---------------------------------------------------------------------------
__global__ __launch_bounds__(256) void scan_k(const float* __restrict__ dtb,
                                              const float* __restrict__ xdbl,
                                              const float* __restrict__ xc,
                                              const float* __restrict__ A_log,
                                              const float* __restrict__ Dp,
                                              const float* __restrict__ xz,
                                              float* __restrict__ y) {
    __shared__ float sdt[2][64][16];
    __shared__ float sxv[2][64][16];
    __shared__ float sB[2][64][16];
    __shared__ float sC[2][64][16];
    __shared__ float sz[2][64][16];
    __shared__ float ys[16][16][17];   // [q][dl][s] pad 17 vs bank conflicts

    const int tid = threadIdx.x;
    const int s = tid & 15;
    const int dl = tid >> 4;
    const int d0 = blockIdx.x * 16;
    const int b = blockIdx.y;

    const float A = -__expf(A_log[(d0 + dl) * 16 + s]);

    // reduce-phase mapping: each wave owns dl range [w*4, w*4+4)
    const int w = tid >> 6;
    const int lane = tid & 63;
    const int r_tt = lane & 15;
    const int r_dl = w * 4 + (lane >> 4);
    const float DpV = Dp[d0 + r_dl];

    // staging mapping: one float4 per array per thread (64 rows x 4 quads)
    const int r4 = tid >> 2;
    const int c4 = (tid & 3) * 4;

    const size_t rowB = (size_t)b * 1024;
    const float* pdt = dtb + (rowB + r4) * 512 + d0 + c4;
    const float* pxv = xc + (rowB + r4) * 512 + d0 + c4;
    const float* pB = xdbl + (rowB + r4) * 48 + 16 + c4;
    const float* pC = xdbl + (rowB + r4) * 48 + 32 + c4;
    const float* pz = xz + (rowB + r4) * 1024 + 512 + d0 + c4;

    // tile 0
    float4 vdt = *(const float4*)pdt;
    float4 vxv = *(const float4*)pxv;
    float4 vB = *(const float4*)pB;
    float4 vC = *(const float4*)pC;
    float4 vz = *(const float4*)pz;
    *(float4*)&sdt[0][r4][c4] = vdt;
    *(float4*)&sxv[0][r4][c4] = vxv;
    *(float4*)&sB[0][r4][c4] = vB;
    *(float4*)&sC[0][r4][c4] = vC;
    *(float4*)&sz[0][r4][c4] = vz;
    __syncthreads();

    float h = 0.f;
    for (int tile = 0; tile < 16; ++tile) {
        const int p = tile & 1;
        if (tile < 15) {  // prefetch next tile into registers (overlaps compute)
            size_t off = (size_t)(tile + 1) * 64;
            vdt = *(const float4*)(pdt + off * 512);
            vxv = *(const float4*)(pxv + off * 512);
            vB = *(const float4*)(pB + off * 48);
            vC = *(const float4*)(pC + off * 48);
            vz = *(const float4*)(pz + off * 1024);
        }
#pragma unroll
        for (int sub = 0; sub < 4; ++sub) {
#pragma unroll
            for (int q = 0; q < 16; ++q) {
                const int tt = sub * 16 + q;
                float dt = sdt[p][tt][dl];
                float xv = sxv[p][tt][dl];
                float Bv = sB[p][tt][s];
                float Cv = sC[p][tt][s];
                float dA = __expf(dt * A);
                h = fmaf(dA, h, dt * xv * Bv);
                ys[q][dl][s] = h * Cv;
            }
            // wave-synchronous: this wave wrote all (dl in its range, s) lanes
            float acc = 0.f;
#pragma unroll
            for (int j = 0; j < 16; ++j)
                acc += ys[r_tt][r_dl][(j + r_tt) & 15];  // stagger vs banks
            const int tt = sub * 16 + r_tt;
            float xvv = sxv[p][tt][r_dl];
            float zv = sz[p][tt][r_dl];
            float sg = zv / (1.f + __expf(-zv));
            y[(rowB + tile * 64 + tt) * 512 + d0 + r_dl] = (acc + DpV * xvv) * sg;
        }
        if (tile < 15) {
            const int pn = p ^ 1;
            *(float4*)&sdt[pn][r4][c4] = vdt;
            *(float4*)&sxv[pn][r4][c4] = vxv;
            *(float4*)&sB[pn][r4][c4] = vB;
            *(float4*)&sC[pn][r4][c4] = vC;
            *(float4*)&sz[pn][r4][c4] = vz;
        }
        __syncthreads();
    }
}

// ---------------------------------------------------------------------------
// Adaptive avg-pool 32x32 -> 8x8 over sequence layout (B, L, C)
// ---------------------------------------------------------------------------
__global__ __launch_bounds__(256) void pool_k(const float* __restrict__ f,
                                              float* __restrict__ feat) {
    int idx = blockIdx.x * 256 + threadIdx.x;  // 8*64*256
    if (idx >= 8 * 64 * 256) return;
    int ch = idx & 255;
    int rc = (idx >> 8) & 63;
    int b = idx >> 14;
    int r = rc >> 3, c = rc & 7;
    float s = 0.f;
#pragma unroll
    for (int i = 0; i < 4; ++i)
#pragma unroll
        for (int j = 0; j < 4; ++j) {
            int l = (r * 4 + i) * 32 + (c * 4 + j);
            s += f[((size_t)b * 1024 + l) * 256 + ch];
        }
    feat[idx] = s * (1.f / 16.f);
}

// ---------------------------------------------------------------------------
// launch
// ---------------------------------------------------------------------------
extern "C" void kernel_launch(void* const* d_in, const int* in_sizes, int n_in,
                              void* d_out, int out_size, void* d_ws, size_t ws_size,
                              hipStream_t stream) {
    const float* x = (const float*)d_in[0];
    const float* conv1_w = (const float*)d_in[1];
    const float* conv1_b = (const float*)d_in[2];
    const float* gn1_g = (const float*)d_in[3];
    const float* gn1_b = (const float*)d_in[4];
    const float* conv2_w = (const float*)d_in[5];
    const float* conv2_b = (const float*)d_in[6];
    const float* gn2_g = (const float*)d_in[7];
    const float* gn2_b = (const float*)d_in[8];
    const float* ln_g = (const float*)d_in[9];
    const float* ln_b = (const float*)d_in[10];
    const float* in_w = (const float*)d_in[11];
    const float* cw = (const float*)d_in[12];
    const float* cb = (const float*)d_in[13];
    const float* xp_w = (const float*)d_in[14];
    const float* dtp_w = (const float*)d_in[15];
    const float* dtp_b = (const float*)d_in[16];
    const float* A_log = (const float*)d_in[17];
    const float* Dp = (const float*)d_in[18];
    const float* out_w = (const float*)d_in[19];
    const float* head_w = (const float*)d_in[20];
    const float* head_b = (const float*)d_in[21];
    float* out = (float*)d_out;

    float* ws = (float*)d_ws;
    float* f = ws + 0;                 // 2,097,152
    float* xn = ws + 2097152;          // 2,097,152
    float* xz = ws + 4194304;          // 8,388,608
    float* xc = ws + 12582912;         // 4,194,304
    float* xdbl = ws + 16777216;       // 393,216
    float* dtb = ws + 17170432;        // 4,194,304
    float* ybuf = ws + 21364736;       // 4,194,304
    float* feat = ws + 25559040;       // 131,072
    float* stats = ws + 25690112;      // 128
    float* h1 = xz;                    // alias: conv stem phase only
    float* h2 = xc;                    // alias: conv stem phase only

    // ---- conv stem ----
    conv1_k<<<(8 * 128 * 64 * 64 + 255) / 256, 256, 0, stream>>>(x, conv1_w, conv1_b, h1);
    gn_stats_k<<<64, 256, 0, stream>>>(h1, stats, 16, 4096);
    gn_apply_k<<<(8 * 128 * 64 * 64 + 255) / 256, 256, 0, stream>>>(h1, stats, gn1_g, gn1_b, 128, 16, 4096, 8 * 128 * 64 * 64);
    conv2_k<<<(8 * 64 * 32 * 32 + 255) / 256, 256, 0, stream>>>(h1, conv2_w, conv2_b, h2);
    gn_stats_k<<<64, 256, 0, stream>>>(h2, stats, 32, 1024);
    gn_apply_k<<<(8 * 256 * 32 * 32 + 255) / 256, 256, 0, stream>>>(h2, stats, gn2_g, gn2_b, 256, 32, 1024, 8 * 256 * 32 * 32);
    transpose_k<<<8192, 256, 0, stream>>>(h2, f);

    // ---- SSM layers ----
    for (int i = 0; i < N_LAYERS; ++i) {
        ln_k<<<2048, 256, 0, stream>>>(f, ln_g + i * 256, ln_b + i * 256, xn);
        gemm_tn<0, 0, 0><<<dim3(16, 128), 256, 0, stream>>>(
            xn, in_w + (size_t)i * 1024 * 256, nullptr, xz, 8192, 1024, 256, 256);
        dwconv_k<<<(8 * 1024 * 512 + 255) / 256, 256, 0, stream>>>(
            xz, cw + i * 512 * 4, cb + i * 512, xc);
        gemm_tn<0, 0, 0><<<dim3(1, 128), 256, 0, stream>>>(
            xc, xp_w + (size_t)i * 48 * 512, nullptr, xdbl, 8192, 48, 512, 512);
        gemm_tn<1, 1, 0><<<dim3(8, 128), 256, 0, stream>>>(
            xdbl, dtp_w + (size_t)i * 512 * 16, dtp_b + i * 512, dtb, 8192, 512, 16, 48);
        scan_k<<<dim3(32, 8), 256, 0, stream>>>(
            dtb, xdbl, xc, A_log + (size_t)i * 512 * 16, Dp + i * 512, xz, ybuf);
        gemm_tn<0, 0, 1><<<dim3(4, 128), 256, 0, stream>>>(
            ybuf, out_w + (size_t)i * 256 * 512, nullptr, f, 8192, 256, 512, 512);
    }

    // ---- pool + heads ----
    pool_k<<<(8 * 64 * 256 + 255) / 256, 256, 0, stream>>>(f, feat);
    for (int d = 0; d < N_DEPTHS; ++d) {
        gemm_tn<1, 0, 0><<<dim3(128, 8), 256, 0, stream>>>(
            feat, head_w + (size_t)d * N_EMB * 256, head_b + (size_t)d * N_EMB,
            out + (size_t)d * BATCH * 64 * N_EMB, 512, N_EMB, 256, 256);
    }
}

// Round 5
// 920.296 us; speedup vs baseline: 4.8605x; 1.8785x over previous
//
#include <hip/hip_runtime.h>
#include <hip/hip_bf16.h>
#include <math.h>

// ---------------------------------------------------------------------------
// RobustDecoder: conv stem -> 4x selective-SSM (Mamba) layers -> pool -> heads
// Round 5: resubmit of round 3/4 (same pod died twice before any bench ran —
// infra failure, not a kernel verdict).
// MFMA bf16 GEMM (m97 structure: 128^2 tile, BK=32, global_load_lds w16,
// b128 frag reads) for conv2-as-im2col, in-proj, xp, out-proj, heads.
// ---------------------------------------------------------------------------

#define D_MODEL 256
#define D_INNER 512
#define N_LAYERS 4
#define N_DEPTHS 4
#define N_EMB 8192
#define BATCH 8

typedef __attribute__((ext_vector_type(8))) short short8;
typedef __attribute__((ext_vector_type(4))) float f32x4;

__device__ __forceinline__ unsigned short f2bf(float x) {
    unsigned u = __float_as_uint(x);
    u = (u + 0x7fffu + ((u >> 16) & 1u)) >> 16;
    return (unsigned short)u;
}

// ---------------------------------------------------------------------------
// conv1: (8,3,128,128) -> (8,128,64,64), 3x3 stride2 pad1, + bias
// ---------------------------------------------------------------------------
__global__ __launch_bounds__(256) void conv1_k(const float* __restrict__ x,
                                               const float* __restrict__ w,
                                               const float* __restrict__ b,
                                               float* __restrict__ out) {
    int idx = blockIdx.x * 256 + threadIdx.x;
    if (idx >= 8 * 128 * 64 * 64) return;
    int ow = idx & 63;
    int oh = (idx >> 6) & 63;
    int oc = (idx >> 12) & 127;
    int bb = idx >> 19;
    float acc = b[oc];
    int ih0 = oh * 2 - 1, iw0 = ow * 2 - 1;
    for (int ic = 0; ic < 3; ++ic) {
        const float* xp = x + ((size_t)(bb * 3 + ic)) * 128 * 128;
        const float* wp = w + ((oc * 3 + ic) * 9);
#pragma unroll
        for (int r = 0; r < 3; ++r) {
            int ih = ih0 + r;
            if ((unsigned)ih < 128u) {
#pragma unroll
                for (int c = 0; c < 3; ++c) {
                    int iw = iw0 + c;
                    if ((unsigned)iw < 128u)
                        acc = fmaf(xp[ih * 128 + iw], wp[r * 3 + c], acc);
                }
            }
        }
    }
    out[idx] = acc;
}

// ---------------------------------------------------------------------------
// GroupNorm stats over contiguous (NCHW) group region
// ---------------------------------------------------------------------------
__global__ __launch_bounds__(256) void gn_stats_k(const float* __restrict__ x,
                                                  float* __restrict__ stats,
                                                  int cpg, int HW) {
    int bg = blockIdx.x;
    const float* xp = x + (size_t)bg * cpg * HW;
    int n = cpg * HW;
    float s = 0.f, ss = 0.f;
    for (int i = threadIdx.x; i < n; i += 256) {
        float v = xp[i];
        s += v;
        ss += v * v;
    }
#pragma unroll
    for (int o = 32; o > 0; o >>= 1) {
        s += __shfl_down(s, o);
        ss += __shfl_down(ss, o);
    }
    __shared__ float sh[4], sh2[4];
    int lane = threadIdx.x & 63, wid = threadIdx.x >> 6;
    if (lane == 0) { sh[wid] = s; sh2[wid] = ss; }
    __syncthreads();
    if (threadIdx.x == 0) {
        float S = sh[0] + sh[1] + sh[2] + sh[3];
        float SS = sh2[0] + sh2[1] + sh2[2] + sh2[3];
        float mean = S / n;
        float var = SS / n - mean * mean;
        stats[bg * 2] = mean;
        stats[bg * 2 + 1] = rsqrtf(var + 1e-5f);
    }
}

// GroupNorm apply + SiLU in place (NCHW)
__global__ __launch_bounds__(256) void gn_apply_k(float* __restrict__ x,
                                                  const float* __restrict__ stats,
                                                  const float* __restrict__ g,
                                                  const float* __restrict__ b,
                                                  int C, int cpg, int HW, int total) {
    int idx = blockIdx.x * 256 + threadIdx.x;
    if (idx >= total) return;
    int ch = (idx / HW) % C;
    int bb = idx / (HW * C);
    int bg = bb * (C / cpg) + ch / cpg;
    float mean = stats[bg * 2], rstd = stats[bg * 2 + 1];
    float v = (x[idx] - mean) * rstd * g[ch] + b[ch];
    x[idx] = v / (1.f + __expf(-v));
}

// ---------------------------------------------------------------------------
// NCHW fp32 -> NHWC bf16 tiled transpose: h1 (8,128,64,64) -> (8,4096,128)
// ---------------------------------------------------------------------------
__global__ __launch_bounds__(256) void nhwc_k(const float* __restrict__ src,
                                              unsigned short* __restrict__ dst) {
    __shared__ float tl[128][65];
    int b = blockIdx.x >> 6;
    int hw0 = (blockIdx.x & 63) * 64;
    int t = threadIdx.x;
#pragma unroll
    for (int p = 0; p < 32; ++p) {
        int c = p * 4 + (t >> 6);
        int hwi = t & 63;
        tl[c][hwi] = src[((size_t)(b * 128 + c)) * 4096 + hw0 + hwi];
    }
    __syncthreads();
#pragma unroll
    for (int p = 0; p < 16; ++p) {
        int hwi = p * 4 + (t >> 6);
        int c0 = (t & 63) * 2;
        unsigned short u0 = f2bf(tl[c0][hwi]);
        unsigned short u1 = f2bf(tl[c0 + 1][hwi]);
        unsigned int pk = (unsigned int)u0 | ((unsigned int)u1 << 16);
        *(unsigned int*)&dst[((size_t)(b * 4096 + hw0 + hwi)) * 128 + c0] = pk;
    }
}

// ---------------------------------------------------------------------------
// im2col (bf16): rows (b,oh,ow) 8192, cols K = (r*3+c)*128 + ic  (1152)
// ---------------------------------------------------------------------------
__global__ __launch_bounds__(256) void im2col_k(const unsigned short* __restrict__ nhwc,
                                                unsigned short* __restrict__ imcol) {
    int idx = blockIdx.x * 256 + threadIdx.x;  // 8192*9*8
    if (idx >= 8192 * 9 * 8) return;
    int chunk = idx & 7;
    int r3c = (idx >> 3) % 9;
    int row = idx / 72;
    int b = row >> 10, l = row & 1023;
    int oh = l >> 5, ow = l & 31;
    int r = r3c / 3, c = r3c % 3;
    int ih = 2 * oh - 1 + r, iw = 2 * ow - 1 + c;
    int4 v0 = make_int4(0, 0, 0, 0), v1 = make_int4(0, 0, 0, 0);
    if ((unsigned)ih < 64u && (unsigned)iw < 64u) {
        const int4* s = (const int4*)&nhwc[((size_t)(b * 4096 + ih * 64 + iw)) * 128 + chunk * 16];
        v0 = s[0];
        v1 = s[1];
    }
    int4* d = (int4*)&imcol[(size_t)row * 1152 + r3c * 128 + chunk * 16];
    d[0] = v0;
    d[1] = v1;
}

// ---------------------------------------------------------------------------
// MFMA bf16 GEMM: C[M,N] = A[M,K]_bf16 @ W[N,K]_bf16^T (+bias) (+=)
// 128x128 tile, 4 waves (2x2), BK=32, global_load_lds w16, b128 frag reads.
// Grid: (ceil(N/128), M/128). W must have grid.x*128 rows (zero-padded).
// ---------------------------------------------------------------------------
template <int BIAS, int ACCUM>
__global__ __launch_bounds__(256) void gemm_bf16(const unsigned short* __restrict__ A,
                                                 const unsigned short* __restrict__ W,
                                                 const float* __restrict__ bias,
                                                 float* __restrict__ C,
                                                 int K, int Nreal, int ldc) {
    __shared__ unsigned short As[128 * 32];
    __shared__ unsigned short Ws[128 * 32];
    const int tid = threadIdx.x;
    const int lane = tid & 63;
    const int w = tid >> 6;
    const int wr = w >> 1, wc = w & 1;
    const int rowBase = blockIdx.y * 128;
    const int colBase = blockIdx.x * 128;

    // staging source bases (lane-dependent); LDS layout resolves to linear
    // As[R*32 + k] == A[rowBase+R][k0+k]
    const int sRow = w * 32 + (lane >> 2);
    const int sK = (lane & 3) * 8;
    const unsigned short* aSrc = A + (size_t)(rowBase + sRow) * K + sK;
    const unsigned short* wSrc = W + (size_t)(colBase + sRow) * K + sK;

    f32x4 acc[4][4];
#pragma unroll
    for (int i = 0; i < 4; ++i)
#pragma unroll
        for (int j = 0; j < 4; ++j)
            acc[i][j] = (f32x4){0.f, 0.f, 0.f, 0.f};

    for (int k0 = 0; k0 < K; k0 += 32) {
#pragma unroll
        for (int c = 0; c < 2; ++c) {
            __builtin_amdgcn_global_load_lds(
                (const __attribute__((address_space(1))) void*)(aSrc + k0 + (size_t)c * 16 * K),
                (__attribute__((address_space(3))) void*)(As + w * 1024 + c * 512), 16, 0, 0);
            __builtin_amdgcn_global_load_lds(
                (const __attribute__((address_space(1))) void*)(wSrc + k0 + (size_t)c * 16 * K),
                (__attribute__((address_space(3))) void*)(Ws + w * 1024 + c * 512), 16, 0, 0);
        }
        __syncthreads();
        short8 af[4], bfr[4];
#pragma unroll
        for (int mi = 0; mi < 4; ++mi)
            af[mi] = *(const short8*)(As + (wr * 64 + mi * 16 + (lane & 15)) * 32 + (lane >> 4) * 8);
#pragma unroll
        for (int ni = 0; ni < 4; ++ni)
            bfr[ni] = *(const short8*)(Ws + (wc * 64 + ni * 16 + (lane & 15)) * 32 + (lane >> 4) * 8);
#pragma unroll
        for (int mi = 0; mi < 4; ++mi)
#pragma unroll
            for (int ni = 0; ni < 4; ++ni)
                acc[mi][ni] = __builtin_amdgcn_mfma_f32_16x16x32_bf16(af[mi], bfr[ni], acc[mi][ni], 0, 0, 0);
        __syncthreads();
    }

#pragma unroll
    for (int mi = 0; mi < 4; ++mi) {
#pragma unroll
        for (int ni = 0; ni < 4; ++ni) {
            int col = colBase + wc * 64 + ni * 16 + (lane & 15);
            if (col < Nreal) {
#pragma unroll
                for (int r = 0; r < 4; ++r) {
                    int row = rowBase + wr * 64 + mi * 16 + (lane >> 4) * 4 + r;
                    float v = acc[mi][ni][r];
                    if (BIAS) v += bias[col];
                    size_t idx = (size_t)row * ldc + col;
                    if (ACCUM)
                        C[idx] += v;
                    else
                        C[idx] = v;
                }
            }
        }
    }
}

// ---------------------------------------------------------------------------
// GroupNorm2 on NHWC layout f (8,1024,256), groups of 32 channels
// ---------------------------------------------------------------------------
__global__ __launch_bounds__(256) void gn2_stats_nhwc_k(const float* __restrict__ f,
                                                        float* __restrict__ stats) {
    int bg = blockIdx.x;  // 64
    int b = bg >> 3, g = bg & 7;
    const float* base = f + (size_t)b * 1024 * 256 + g * 32;
    float s = 0.f, ss = 0.f;
    for (int i = threadIdx.x; i < 32768; i += 256) {
        int hw = i >> 5, c = i & 31;
        float v = base[(size_t)hw * 256 + c];
        s += v;
        ss += v * v;
    }
#pragma unroll
    for (int o = 32; o > 0; o >>= 1) {
        s += __shfl_down(s, o);
        ss += __shfl_down(ss, o);
    }
    __shared__ float sh[4], sh2[4];
    int lane = threadIdx.x & 63, wid = threadIdx.x >> 6;
    if (lane == 0) { sh[wid] = s; sh2[wid] = ss; }
    __syncthreads();
    if (threadIdx.x == 0) {
        float S = sh[0] + sh[1] + sh[2] + sh[3];
        float SS = sh2[0] + sh2[1] + sh2[2] + sh2[3];
        float mean = S / 32768.f;
        float var = SS / 32768.f - mean * mean;
        stats[bg * 2] = mean;
        stats[bg * 2 + 1] = rsqrtf(var + 1e-5f);
    }
}

__global__ __launch_bounds__(256) void gn2_apply_nhwc_k(float* __restrict__ f,
                                                        const float* __restrict__ stats,
                                                        const float* __restrict__ g,
                                                        const float* __restrict__ b) {
    int idx = blockIdx.x * 256 + threadIdx.x;
    if (idx >= 8 * 1024 * 256) return;
    int c = idx & 255;
    int bb = idx >> 18;
    int bg = bb * 8 + (c >> 5);
    float mean = stats[bg * 2], rstd = stats[bg * 2 + 1];
    float v = (f[idx] - mean) * rstd * g[c] + b[c];
    f[idx] = v / (1.f + __expf(-v));
}

// ---------------------------------------------------------------------------
// LayerNorm (dim 256) -> bf16 output
// ---------------------------------------------------------------------------
__global__ __launch_bounds__(256) void ln_k(const float* __restrict__ f,
                                            const float* __restrict__ g,
                                            const float* __restrict__ b,
                                            unsigned short* __restrict__ xn) {
    int row = blockIdx.x * 4 + (threadIdx.x >> 6);
    int lane = threadIdx.x & 63;
    const float* xp = f + (size_t)row * 256;
    float4 v = *(const float4*)(xp + lane * 4);
    float s = v.x + v.y + v.z + v.w;
#pragma unroll
    for (int o = 32; o > 0; o >>= 1) s += __shfl_xor(s, o);
    float mean = s * (1.f / 256.f);
    float dx = v.x - mean, dy = v.y - mean, dz = v.z - mean, dw = v.w - mean;
    float ss = dx * dx + dy * dy + dz * dz + dw * dw;
#pragma unroll
    for (int o = 32; o > 0; o >>= 1) ss += __shfl_xor(ss, o);
    float rstd = rsqrtf(ss * (1.f / 256.f) + 1e-5f);
    float4 gg = *(const float4*)(g + lane * 4);
    float4 bb = *(const float4*)(b + lane * 4);
    ushort4 o4;
    o4.x = f2bf(dx * rstd * gg.x + bb.x);
    o4.y = f2bf(dy * rstd * gg.y + bb.y);
    o4.z = f2bf(dz * rstd * gg.z + bb.z);
    o4.w = f2bf(dw * rstd * gg.w + bb.w);
    *(ushort4*)(xn + (size_t)row * 256 + lane * 4) = o4;
}

// ---------------------------------------------------------------------------
// fp32 GEMM (kept for dt-proj, K=16): C = softplus(A@W^T + bias)
// ---------------------------------------------------------------------------
template <int BIAS, int ACT, int ACCUM>
__global__ __launch_bounds__(256) void gemm_tn(const float* __restrict__ A,
                                               const float* __restrict__ W,
                                               const float* __restrict__ bias,
                                               float* __restrict__ C,
                                               int M, int N, int K, int lda) {
    __shared__ float As[16][68];
    __shared__ float Ws[16][68];
    const int t = threadIdx.x;
    const int tx = t & 15;
    const int ty = t >> 4;
    const int rowBase = blockIdx.y * 64;
    const int colBase = blockIdx.x * 64;
    const int lRow = t >> 2;
    const int lK = (t & 3) * 4;
    float acc[4][4] = {};
    for (int k0 = 0; k0 < K; k0 += 16) {
        {
            const float* src = A + (size_t)(rowBase + lRow) * lda + k0 + lK;
            float4 v = *(const float4*)src;
            As[lK + 0][lRow] = v.x;
            As[lK + 1][lRow] = v.y;
            As[lK + 2][lRow] = v.z;
            As[lK + 3][lRow] = v.w;
        }
        {
            int n = colBase + lRow;
            float4 v = make_float4(0.f, 0.f, 0.f, 0.f);
            if (n < N) v = *(const float4*)(W + (size_t)n * K + k0 + lK);
            Ws[lK + 0][lRow] = v.x;
            Ws[lK + 1][lRow] = v.y;
            Ws[lK + 2][lRow] = v.z;
            Ws[lK + 3][lRow] = v.w;
        }
        __syncthreads();
#pragma unroll
        for (int kk = 0; kk < 16; ++kk) {
            float4 a4 = *(const float4*)&As[kk][ty * 4];
            float4 w4 = *(const float4*)&Ws[kk][tx * 4];
            float av[4] = {a4.x, a4.y, a4.z, a4.w};
            float wv[4] = {w4.x, w4.y, w4.z, w4.w};
#pragma unroll
            for (int i = 0; i < 4; ++i)
#pragma unroll
                for (int j = 0; j < 4; ++j)
                    acc[i][j] = fmaf(av[i], wv[j], acc[i][j]);
        }
        __syncthreads();
    }
#pragma unroll
    for (int i = 0; i < 4; ++i) {
        int row = rowBase + ty * 4 + i;
#pragma unroll
        for (int j = 0; j < 4; ++j) {
            int col = colBase + tx * 4 + j;
            if (col < N) {
                float v = acc[i][j];
                if (BIAS) v += bias[col];
                if (ACT == 1) v = (v > 20.f) ? v : log1pf(__expf(v));
                size_t idx = (size_t)row * N + col;
                if (ACCUM)
                    C[idx] += v;
                else
                    C[idx] = v;
            }
        }
    }
}

// ---------------------------------------------------------------------------
// Causal depthwise conv1d (k=4) + bias + SiLU; writes fp32 xc and bf16 xcb
// ---------------------------------------------------------------------------
__global__ __launch_bounds__(256) void dwconv_k(const float* __restrict__ xz,
                                                const float* __restrict__ cw,
                                                const float* __restrict__ cb,
                                                float* __restrict__ xc,
                                                unsigned short* __restrict__ xcb) {
    int idx = blockIdx.x * 256 + threadIdx.x;  // 8*1024*512
    if (idx >= 8 * 1024 * 512) return;
    int d = idx & 511;
    int tt = (idx >> 9) & 1023;
    int b = idx >> 19;
    const float* xp = xz + (size_t)b * 1024 * 1024 + d;
    float w0 = cw[d * 4], w1 = cw[d * 4 + 1], w2 = cw[d * 4 + 2], w3 = cw[d * 4 + 3];
    float acc = cb[d];
    if (tt >= 3) acc = fmaf(xp[(size_t)(tt - 3) * 1024], w0, acc);
    if (tt >= 2) acc = fmaf(xp[(size_t)(tt - 2) * 1024], w1, acc);
    if (tt >= 1) acc = fmaf(xp[(size_t)(tt - 1) * 1024], w2, acc);
    acc = fmaf(xp[(size_t)tt * 1024], w3, acc);
    float v = acc / (1.f + __expf(-acc));
    xc[idx] = v;
    xcb[idx] = f2bf(v);
}

// ---------------------------------------------------------------------------
// Selective scan (as round 2) -> bf16 y
// ---------------------------------------------------------------------------
__global__ __launch_bounds__(256) void scan_k(const float* __restrict__ dtb,
                                              const float* __restrict__ xdbl,
                                              const float* __restrict__ xc,
                                              const float* __restrict__ A_log,
                                              const float* __restrict__ Dp,
                                              const float* __restrict__ xz,
                                              unsigned short* __restrict__ y) {
    __shared__ float sdt[2][64][16];
    __shared__ float sxv[2][64][16];
    __shared__ float sB[2][64][16];
    __shared__ float sC[2][64][16];
    __shared__ float sz[2][64][16];
    __shared__ float ys[16][16][17];

    const int tid = threadIdx.x;
    const int s = tid & 15;
    const int dl = tid >> 4;
    const int d0 = blockIdx.x * 16;
    const int b = blockIdx.y;

    const float A = -__expf(A_log[(d0 + dl) * 16 + s]);

    const int w = tid >> 6;
    const int lane = tid & 63;
    const int r_tt = lane & 15;
    const int r_dl = w * 4 + (lane >> 4);
    const float DpV = Dp[d0 + r_dl];

    const int r4 = tid >> 2;
    const int c4 = (tid & 3) * 4;

    const size_t rowB = (size_t)b * 1024;
    const float* pdt = dtb + (rowB + r4) * 512 + d0 + c4;
    const float* pxv = xc + (rowB + r4) * 512 + d0 + c4;
    const float* pB = xdbl + (rowB + r4) * 48 + 16 + c4;
    const float* pC = xdbl + (rowB + r4) * 48 + 32 + c4;
    const float* pz = xz + (rowB + r4) * 1024 + 512 + d0 + c4;

    float4 vdt = *(const float4*)pdt;
    float4 vxv = *(const float4*)pxv;
    float4 vB = *(const float4*)pB;
    float4 vC = *(const float4*)pC;
    float4 vz = *(const float4*)pz;
    *(float4*)&sdt[0][r4][c4] = vdt;
    *(float4*)&sxv[0][r4][c4] = vxv;
    *(float4*)&sB[0][r4][c4] = vB;
    *(float4*)&sC[0][r4][c4] = vC;
    *(float4*)&sz[0][r4][c4] = vz;
    __syncthreads();

    float h = 0.f;
    for (int tile = 0; tile < 16; ++tile) {
        const int p = tile & 1;
        if (tile < 15) {
            size_t off = (size_t)(tile + 1) * 64;
            vdt = *(const float4*)(pdt + off * 512);
            vxv = *(const float4*)(pxv + off * 512);
            vB = *(const float4*)(pB + off * 48);
            vC = *(const float4*)(pC + off * 48);
            vz = *(const float4*)(pz + off * 1024);
        }
#pragma unroll
        for (int sub = 0; sub < 4; ++sub) {
#pragma unroll
            for (int q = 0; q < 16; ++q) {
                const int tt = sub * 16 + q;
                float dt = sdt[p][tt][dl];
                float xv = sxv[p][tt][dl];
                float Bv = sB[p][tt][s];
                float Cv = sC[p][tt][s];
                float dA = __expf(dt * A);
                h = fmaf(dA, h, dt * xv * Bv);
                ys[q][dl][s] = h * Cv;
            }
            float acc = 0.f;
#pragma unroll
            for (int j = 0; j < 16; ++j)
                acc += ys[r_tt][r_dl][(j + r_tt) & 15];
            const int tt = sub * 16 + r_tt;
            float xvv = sxv[p][tt][r_dl];
            float zv = sz[p][tt][r_dl];
            float sg = zv / (1.f + __expf(-zv));
            y[(rowB + tile * 64 + tt) * 512 + d0 + r_dl] = f2bf((acc + DpV * xvv) * sg);
        }
        if (tile < 15) {
            const int pn = p ^ 1;
            *(float4*)&sdt[pn][r4][c4] = vdt;
            *(float4*)&sxv[pn][r4][c4] = vxv;
            *(float4*)&sB[pn][r4][c4] = vB;
            *(float4*)&sC[pn][r4][c4] = vC;
            *(float4*)&sz[pn][r4][c4] = vz;
        }
        __syncthreads();
    }
}

// ---------------------------------------------------------------------------
// Adaptive avg-pool 32x32 -> 8x8 over (B, L, C) -> bf16 feat
// ---------------------------------------------------------------------------
__global__ __launch_bounds__(256) void pool_k(const float* __restrict__ f,
                                              unsigned short* __restrict__ feat) {
    int idx = blockIdx.x * 256 + threadIdx.x;  // 8*64*256
    if (idx >= 8 * 64 * 256) return;
    int ch = idx & 255;
    int rc = (idx >> 8) & 63;
    int b = idx >> 14;
    int r = rc >> 3, c = rc & 7;
    float s = 0.f;
#pragma unroll
    for (int i = 0; i < 4; ++i)
#pragma unroll
        for (int j = 0; j < 4; ++j) {
            int l = (r * 4 + i) * 32 + (c * 4 + j);
            s += f[((size_t)b * 1024 + l) * 256 + ch];
        }
    feat[idx] = f2bf(s * (1.f / 16.f));
}

// ---------------------------------------------------------------------------
// weight conversion helpers
// ---------------------------------------------------------------------------
__global__ __launch_bounds__(256) void cvt_k(const float* __restrict__ s,
                                             unsigned short* __restrict__ d, int n4) {
    int i = blockIdx.x * 256 + threadIdx.x;
    if (i >= n4) return;
    float4 v = *(const float4*)(s + (size_t)i * 4);
    ushort4 u;
    u.x = f2bf(v.x);
    u.y = f2bf(v.y);
    u.z = f2bf(v.z);
    u.w = f2bf(v.w);
    *(ushort4*)(d + (size_t)i * 4) = u;
}

// xp_w (4,48,512) -> (4,128,512) zero-padded bf16
__global__ __launch_bounds__(256) void xpw_pad_k(const float* __restrict__ s,
                                                 unsigned short* __restrict__ d) {
    int idx = blockIdx.x * 256 + threadIdx.x;  // 4*128*512
    if (idx >= 4 * 128 * 512) return;
    int l = idx >> 16;
    int n = (idx >> 9) & 127;
    int k = idx & 511;
    d[idx] = (n < 48) ? f2bf(s[((size_t)l * 48 + n) * 512 + k]) : (unsigned short)0;
}

// conv2_w (256,128,3,3) -> w2col (256, (r*3+c)*128+ic) bf16
__global__ __launch_bounds__(256) void w2col_k(const float* __restrict__ s,
                                               unsigned short* __restrict__ d) {
    int idx = blockIdx.x * 256 + threadIdx.x;  // 256*1152
    if (idx >= 256 * 1152) return;
    int oc = idx / 1152;
    int kk = idx % 1152;
    int r3c = kk >> 7;
    int ic = kk & 127;
    d[idx] = f2bf(s[((size_t)(oc * 128 + ic)) * 9 + r3c]);
}

// ---------------------------------------------------------------------------
// launch
// ---------------------------------------------------------------------------
extern "C" void kernel_launch(void* const* d_in, const int* in_sizes, int n_in,
                              void* d_out, int out_size, void* d_ws, size_t ws_size,
                              hipStream_t stream) {
    const float* x = (const float*)d_in[0];
    const float* conv1_w = (const float*)d_in[1];
    const float* conv1_b = (const float*)d_in[2];
    const float* gn1_g = (const float*)d_in[3];
    const float* gn1_b = (const float*)d_in[4];
    const float* conv2_w = (const float*)d_in[5];
    const float* conv2_b = (const float*)d_in[6];
    const float* gn2_g = (const float*)d_in[7];
    const float* gn2_b = (const float*)d_in[8];
    const float* ln_g = (const float*)d_in[9];
    const float* ln_b = (const float*)d_in[10];
    const float* in_w = (const float*)d_in[11];
    const float* cw = (const float*)d_in[12];
    const float* cb = (const float*)d_in[13];
    const float* xp_w = (const float*)d_in[14];
    const float* dtp_w = (const float*)d_in[15];
    const float* dtp_b = (const float*)d_in[16];
    const float* A_log = (const float*)d_in[17];
    const float* Dp = (const float*)d_in[18];
    const float* out_w = (const float*)d_in[19];
    const float* head_w = (const float*)d_in[20];
    const float* head_b = (const float*)d_in[21];
    float* out = (float*)d_out;

    char* ws = (char*)d_ws;
    // byte layout (all 256B aligned), total ~102.3 MB
    float* f = (float*)(ws + 0);                         //  8,388,608
    float* xz = (float*)(ws + 8388608);                  // 33,554,432 (stem: h1 fp32 / imcol bf16)
    float* xc = (float*)(ws + 41943040);                 // 16,777,216 (tail: headw_b)
    float* xdbl = (float*)(ws + 58720256);               //  1,572,864 (tail: feat_b)
    float* dtb = (float*)(ws + 60293120);                // 16,777,216 (stem: h1nhwc bf16)
    unsigned short* xn_b = (unsigned short*)(ws + 77070336);    // 4,194,304
    unsigned short* xcb = (unsigned short*)(ws + 81264640);     // 8,388,608
    unsigned short* ybuf_b = (unsigned short*)(ws + 89653248);  // 8,388,608
    unsigned short* w2col_b = (unsigned short*)(ws + 98041856); //   589,824
    unsigned short* inw_b = (unsigned short*)(ws + 98631680);   // 2,097,152
    unsigned short* xpw_b = (unsigned short*)(ws + 100728832);  //   524,288
    unsigned short* outw_b = (unsigned short*)(ws + 101253120); // 1,048,576
    float* stats = (float*)(ws + 102301696);             // 512

    float* h1 = xz;                                      // stem alias
    unsigned short* h1n = (unsigned short*)dtb;          // stem alias
    unsigned short* imcol = (unsigned short*)xz;         // stem alias (after h1 dead)
    unsigned short* headw_b = (unsigned short*)xc;       // tail alias
    unsigned short* feat_b = (unsigned short*)xdbl;      // tail alias

    // ---- weight conversions ----
    w2col_k<<<(256 * 1152 + 255) / 256, 256, 0, stream>>>(conv2_w, w2col_b);
    cvt_k<<<(1048576 / 4 + 255) / 256, 256, 0, stream>>>(in_w, inw_b, 1048576 / 4);
    xpw_pad_k<<<(4 * 128 * 512 + 255) / 256, 256, 0, stream>>>(xp_w, xpw_b);
    cvt_k<<<(524288 / 4 + 255) / 256, 256, 0, stream>>>(out_w, outw_b, 524288 / 4);

    // ---- conv stem ----
    conv1_k<<<(8 * 128 * 64 * 64 + 255) / 256, 256, 0, stream>>>(x, conv1_w, conv1_b, h1);
    gn_stats_k<<<64, 256, 0, stream>>>(h1, stats, 16, 4096);
    gn_apply_k<<<(8 * 128 * 64 * 64 + 255) / 256, 256, 0, stream>>>(h1, stats, gn1_g, gn1_b, 128, 16, 4096, 8 * 128 * 64 * 64);
    nhwc_k<<<512, 256, 0, stream>>>(h1, h1n);
    im2col_k<<<(8192 * 9 * 8 + 255) / 256, 256, 0, stream>>>(h1n, imcol);
    gemm_bf16<1, 0><<<dim3(2, 64), 256, 0, stream>>>(imcol, w2col_b, conv2_b, f, 1152, 256, 256);
    gn2_stats_nhwc_k<<<64, 256, 0, stream>>>(f, stats);
    gn2_apply_nhwc_k<<<(8 * 1024 * 256 + 255) / 256, 256, 0, stream>>>(f, stats, gn2_g, gn2_b);

    // ---- SSM layers ----
    for (int i = 0; i < N_LAYERS; ++i) {
        ln_k<<<2048, 256, 0, stream>>>(f, ln_g + i * 256, ln_b + i * 256, xn_b);
        gemm_bf16<0, 0><<<dim3(8, 64), 256, 0, stream>>>(
            xn_b, inw_b + (size_t)i * 1024 * 256, nullptr, xz, 256, 1024, 1024);
        dwconv_k<<<(8 * 1024 * 512 + 255) / 256, 256, 0, stream>>>(
            xz, cw + i * 512 * 4, cb + i * 512, xc, xcb);
        gemm_bf16<0, 0><<<dim3(1, 64), 256, 0, stream>>>(
            xcb, xpw_b + (size_t)i * 128 * 512, nullptr, xdbl, 512, 48, 48);
        gemm_tn<1, 1, 0><<<dim3(8, 128), 256, 0, stream>>>(
            xdbl, dtp_w + (size_t)i * 512 * 16, dtp_b + i * 512, dtb, 8192, 512, 16, 48);
        scan_k<<<dim3(32, 8), 256, 0, stream>>>(
            dtb, xdbl, xc, A_log + (size_t)i * 512 * 16, Dp + i * 512, xz, ybuf_b);
        gemm_bf16<0, 1><<<dim3(2, 64), 256, 0, stream>>>(
            ybuf_b, outw_b + (size_t)i * 256 * 512, nullptr, f, 512, 256, 256);
    }

    // ---- pool + heads ----
    cvt_k<<<(8388608 / 4 + 255) / 256, 256, 0, stream>>>(head_w, headw_b, 8388608 / 4);
    pool_k<<<(8 * 64 * 256 + 255) / 256, 256, 0, stream>>>(f, feat_b);
    for (int d = 0; d < N_DEPTHS; ++d) {
        gemm_bf16<1, 0><<<dim3(64, 4), 256, 0, stream>>>(
            feat_b, headw_b + (size_t)d * N_EMB * 256, head_b + (size_t)d * N_EMB,
            out + (size_t)d * BATCH * 64 * N_EMB, 256, N_EMB, N_EMB);
    }
}

// Round 6
// 837.089 us; speedup vs baseline: 5.3437x; 1.0994x over previous
//
#include <hip/hip_runtime.h>
#include <hip/hip_bf16.h>
#include <math.h>

// ---------------------------------------------------------------------------
// RobustDecoder: conv stem -> 4x selective-SSM (Mamba) layers -> pool -> heads
// Round 6: scan v3 (transposed LDS + DPP row_ror allreduce, no ys round-trip),
// conv1 v2 (LDS-tiled, 32-oc/thread, broadcast weights), dwconv bf16-only out.
// ---------------------------------------------------------------------------

#define D_MODEL 256
#define D_INNER 512
#define N_LAYERS 4
#define N_DEPTHS 4
#define N_EMB 8192
#define BATCH 8

typedef __attribute__((ext_vector_type(8))) short short8;
typedef __attribute__((ext_vector_type(4))) float f32x4;

__device__ __forceinline__ unsigned short f2bf(float x) {
    unsigned u = __float_as_uint(x);
    u = (u + 0x7fffu + ((u >> 16) & 1u)) >> 16;
    return (unsigned short)u;
}

template <int CTRL>
__device__ __forceinline__ float dpp_add(float v) {
    int t = __builtin_amdgcn_update_dpp(0, __float_as_int(v), CTRL, 0xf, 0xf, true);
    return v + __int_as_float(t);
}

// ---------------------------------------------------------------------------
// conv1 v2: (8,3,128,128) -> (8,128,64,64), 3x3 stride2 pad1, + bias
// block = (b, 8x8 output tile), all 128 oc. x-patch + weights in LDS.
// thread = (pixel 0..63, oc-group 0..3 of 32): w float4 wave-broadcast reads.
// ---------------------------------------------------------------------------
__global__ __launch_bounds__(256) void conv1_k(const float* __restrict__ x,
                                               const float* __restrict__ w,
                                               const float* __restrict__ b,
                                               float* __restrict__ out) {
    __shared__ float xs[3][17][18];
    __shared__ float wsm[128][28];
    const int tid = threadIdx.x;
    const int bb = blockIdx.x >> 6;
    const int tile = blockIdx.x & 63;
    const int oh0 = (tile >> 3) * 8, ow0 = (tile & 7) * 8;

    for (int i = tid; i < 3456; i += 256) wsm[i / 27][i % 27] = w[i];
    for (int i = tid; i < 128; i += 256) wsm[i][27] = 0.f;

    const int ih0 = oh0 * 2 - 1, iw0 = ow0 * 2 - 1;
    for (int i = tid; i < 3 * 289; i += 256) {
        int ic = i / 289, rr = (i % 289) / 17, cc = i % 17;
        int ih = ih0 + rr, iw = iw0 + cc;
        float v = 0.f;
        if ((unsigned)ih < 128u && (unsigned)iw < 128u)
            v = x[((size_t)(bb * 3 + ic) * 128 + ih) * 128 + iw];
        xs[ic][rr][cc] = v;
    }
    __syncthreads();

    const int px = tid & 63, ph = px >> 3, pw = px & 7;
    const int oc0 = (tid >> 6) * 32;
    float xk[28];
#pragma unroll
    for (int ic = 0; ic < 3; ++ic)
#pragma unroll
        for (int r = 0; r < 3; ++r)
#pragma unroll
            for (int c = 0; c < 3; ++c)
                xk[ic * 9 + r * 3 + c] = xs[ic][ph * 2 + r][pw * 2 + c];
    xk[27] = 0.f;

    size_t obase = ((size_t)(bb * 128 + oc0) * 64 + oh0 + ph) * 64 + ow0 + pw;
#pragma unroll
    for (int oc = 0; oc < 32; ++oc) {
        float a = b[oc0 + oc];
#pragma unroll
        for (int k4 = 0; k4 < 7; ++k4) {
            float4 w4 = *(const float4*)&wsm[oc0 + oc][k4 * 4];
            a = fmaf(xk[k4 * 4 + 0], w4.x, a);
            a = fmaf(xk[k4 * 4 + 1], w4.y, a);
            a = fmaf(xk[k4 * 4 + 2], w4.z, a);
            a = fmaf(xk[k4 * 4 + 3], w4.w, a);
        }
        out[obase + (size_t)oc * 4096] = a;
    }
}

// ---------------------------------------------------------------------------
// GroupNorm stats over contiguous (NCHW) group region
// ---------------------------------------------------------------------------
__global__ __launch_bounds__(256) void gn_stats_k(const float* __restrict__ x,
                                                  float* __restrict__ stats,
                                                  int cpg, int HW) {
    int bg = blockIdx.x;
    const float* xp = x + (size_t)bg * cpg * HW;
    int n = cpg * HW;
    float s = 0.f, ss = 0.f;
    for (int i = threadIdx.x; i < n; i += 256) {
        float v = xp[i];
        s += v;
        ss += v * v;
    }
#pragma unroll
    for (int o = 32; o > 0; o >>= 1) {
        s += __shfl_down(s, o);
        ss += __shfl_down(ss, o);
    }
    __shared__ float sh[4], sh2[4];
    int lane = threadIdx.x & 63, wid = threadIdx.x >> 6;
    if (lane == 0) { sh[wid] = s; sh2[wid] = ss; }
    __syncthreads();
    if (threadIdx.x == 0) {
        float S = sh[0] + sh[1] + sh[2] + sh[3];
        float SS = sh2[0] + sh2[1] + sh2[2] + sh2[3];
        float mean = S / n;
        float var = SS / n - mean * mean;
        stats[bg * 2] = mean;
        stats[bg * 2 + 1] = rsqrtf(var + 1e-5f);
    }
}

// GroupNorm apply + SiLU in place (NCHW)
__global__ __launch_bounds__(256) void gn_apply_k(float* __restrict__ x,
                                                  const float* __restrict__ stats,
                                                  const float* __restrict__ g,
                                                  const float* __restrict__ b,
                                                  int C, int cpg, int HW, int total) {
    int idx = blockIdx.x * 256 + threadIdx.x;
    if (idx >= total) return;
    int ch = (idx / HW) % C;
    int bb = idx / (HW * C);
    int bg = bb * (C / cpg) + ch / cpg;
    float mean = stats[bg * 2], rstd = stats[bg * 2 + 1];
    float v = (x[idx] - mean) * rstd * g[ch] + b[ch];
    x[idx] = v / (1.f + __expf(-v));
}

// ---------------------------------------------------------------------------
// NCHW fp32 -> NHWC bf16 tiled transpose: h1 (8,128,64,64) -> (8,4096,128)
// ---------------------------------------------------------------------------
__global__ __launch_bounds__(256) void nhwc_k(const float* __restrict__ src,
                                              unsigned short* __restrict__ dst) {
    __shared__ float tl[128][65];
    int b = blockIdx.x >> 6;
    int hw0 = (blockIdx.x & 63) * 64;
    int t = threadIdx.x;
#pragma unroll
    for (int p = 0; p < 32; ++p) {
        int c = p * 4 + (t >> 6);
        int hwi = t & 63;
        tl[c][hwi] = src[((size_t)(b * 128 + c)) * 4096 + hw0 + hwi];
    }
    __syncthreads();
#pragma unroll
    for (int p = 0; p < 16; ++p) {
        int hwi = p * 4 + (t >> 6);
        int c0 = (t & 63) * 2;
        unsigned short u0 = f2bf(tl[c0][hwi]);
        unsigned short u1 = f2bf(tl[c0 + 1][hwi]);
        unsigned int pk = (unsigned int)u0 | ((unsigned int)u1 << 16);
        *(unsigned int*)&dst[((size_t)(b * 4096 + hw0 + hwi)) * 128 + c0] = pk;
    }
}

// ---------------------------------------------------------------------------
// im2col (bf16): rows (b,oh,ow) 8192, cols K = (r*3+c)*128 + ic  (1152)
// ---------------------------------------------------------------------------
__global__ __launch_bounds__(256) void im2col_k(const unsigned short* __restrict__ nhwc,
                                                unsigned short* __restrict__ imcol) {
    int idx = blockIdx.x * 256 + threadIdx.x;  // 8192*9*8
    if (idx >= 8192 * 9 * 8) return;
    int chunk = idx & 7;
    int r3c = (idx >> 3) % 9;
    int row = idx / 72;
    int b = row >> 10, l = row & 1023;
    int oh = l >> 5, ow = l & 31;
    int r = r3c / 3, c = r3c % 3;
    int ih = 2 * oh - 1 + r, iw = 2 * ow - 1 + c;
    int4 v0 = make_int4(0, 0, 0, 0), v1 = make_int4(0, 0, 0, 0);
    if ((unsigned)ih < 64u && (unsigned)iw < 64u) {
        const int4* s = (const int4*)&nhwc[((size_t)(b * 4096 + ih * 64 + iw)) * 128 + chunk * 16];
        v0 = s[0];
        v1 = s[1];
    }
    int4* d = (int4*)&imcol[(size_t)row * 1152 + r3c * 128 + chunk * 16];
    d[0] = v0;
    d[1] = v1;
}

// ---------------------------------------------------------------------------
// MFMA bf16 GEMM: C[M,N] = A[M,K]_bf16 @ W[N,K]_bf16^T (+bias) (+=)
// 128x128 tile, 4 waves (2x2), BK=32, global_load_lds w16, b128 frag reads.
// ---------------------------------------------------------------------------
template <int BIAS, int ACCUM>
__global__ __launch_bounds__(256) void gemm_bf16(const unsigned short* __restrict__ A,
                                                 const unsigned short* __restrict__ W,
                                                 const float* __restrict__ bias,
                                                 float* __restrict__ C,
                                                 int K, int Nreal, int ldc) {
    __shared__ unsigned short As[128 * 32];
    __shared__ unsigned short Ws[128 * 32];
    const int tid = threadIdx.x;
    const int lane = tid & 63;
    const int w = tid >> 6;
    const int wr = w >> 1, wc = w & 1;
    const int rowBase = blockIdx.y * 128;
    const int colBase = blockIdx.x * 128;

    const int sRow = w * 32 + (lane >> 2);
    const int sK = (lane & 3) * 8;
    const unsigned short* aSrc = A + (size_t)(rowBase + sRow) * K + sK;
    const unsigned short* wSrc = W + (size_t)(colBase + sRow) * K + sK;

    f32x4 acc[4][4];
#pragma unroll
    for (int i = 0; i < 4; ++i)
#pragma unroll
        for (int j = 0; j < 4; ++j)
            acc[i][j] = (f32x4){0.f, 0.f, 0.f, 0.f};

    for (int k0 = 0; k0 < K; k0 += 32) {
#pragma unroll
        for (int c = 0; c < 2; ++c) {
            __builtin_amdgcn_global_load_lds(
                (const __attribute__((address_space(1))) void*)(aSrc + k0 + (size_t)c * 16 * K),
                (__attribute__((address_space(3))) void*)(As + w * 1024 + c * 512), 16, 0, 0);
            __builtin_amdgcn_global_load_lds(
                (const __attribute__((address_space(1))) void*)(wSrc + k0 + (size_t)c * 16 * K),
                (__attribute__((address_space(3))) void*)(Ws + w * 1024 + c * 512), 16, 0, 0);
        }
        __syncthreads();
        short8 af[4], bfr[4];
#pragma unroll
        for (int mi = 0; mi < 4; ++mi)
            af[mi] = *(const short8*)(As + (wr * 64 + mi * 16 + (lane & 15)) * 32 + (lane >> 4) * 8);
#pragma unroll
        for (int ni = 0; ni < 4; ++ni)
            bfr[ni] = *(const short8*)(Ws + (wc * 64 + ni * 16 + (lane & 15)) * 32 + (lane >> 4) * 8);
#pragma unroll
        for (int mi = 0; mi < 4; ++mi)
#pragma unroll
            for (int ni = 0; ni < 4; ++ni)
                acc[mi][ni] = __builtin_amdgcn_mfma_f32_16x16x32_bf16(af[mi], bfr[ni], acc[mi][ni], 0, 0, 0);
        __syncthreads();
    }

#pragma unroll
    for (int mi = 0; mi < 4; ++mi) {
#pragma unroll
        for (int ni = 0; ni < 4; ++ni) {
            int col = colBase + wc * 64 + ni * 16 + (lane & 15);
            if (col < Nreal) {
#pragma unroll
                for (int r = 0; r < 4; ++r) {
                    int row = rowBase + wr * 64 + mi * 16 + (lane >> 4) * 4 + r;
                    float v = acc[mi][ni][r];
                    if (BIAS) v += bias[col];
                    size_t idx = (size_t)row * ldc + col;
                    if (ACCUM)
                        C[idx] += v;
                    else
                        C[idx] = v;
                }
            }
        }
    }
}

// ---------------------------------------------------------------------------
// GroupNorm2 on NHWC layout f (8,1024,256), groups of 32 channels
// ---------------------------------------------------------------------------
__global__ __launch_bounds__(256) void gn2_stats_nhwc_k(const float* __restrict__ f,
                                                        float* __restrict__ stats) {
    int bg = blockIdx.x;  // 64
    int b = bg >> 3, g = bg & 7;
    const float* base = f + (size_t)b * 1024 * 256 + g * 32;
    float s = 0.f, ss = 0.f;
    for (int i = threadIdx.x; i < 32768; i += 256) {
        int hw = i >> 5, c = i & 31;
        float v = base[(size_t)hw * 256 + c];
        s += v;
        ss += v * v;
    }
#pragma unroll
    for (int o = 32; o > 0; o >>= 1) {
        s += __shfl_down(s, o);
        ss += __shfl_down(ss, o);
    }
    __shared__ float sh[4], sh2[4];
    int lane = threadIdx.x & 63, wid = threadIdx.x >> 6;
    if (lane == 0) { sh[wid] = s; sh2[wid] = ss; }
    __syncthreads();
    if (threadIdx.x == 0) {
        float S = sh[0] + sh[1] + sh[2] + sh[3];
        float SS = sh2[0] + sh2[1] + sh2[2] + sh2[3];
        float mean = S / 32768.f;
        float var = SS / 32768.f - mean * mean;
        stats[bg * 2] = mean;
        stats[bg * 2 + 1] = rsqrtf(var + 1e-5f);
    }
}

__global__ __launch_bounds__(256) void gn2_apply_nhwc_k(float* __restrict__ f,
                                                        const float* __restrict__ stats,
                                                        const float* __restrict__ g,
                                                        const float* __restrict__ b) {
    int idx = blockIdx.x * 256 + threadIdx.x;
    if (idx >= 8 * 1024 * 256) return;
    int c = idx & 255;
    int bb = idx >> 18;
    int bg = bb * 8 + (c >> 5);
    float mean = stats[bg * 2], rstd = stats[bg * 2 + 1];
    float v = (f[idx] - mean) * rstd * g[c] + b[c];
    f[idx] = v / (1.f + __expf(-v));
}

// ---------------------------------------------------------------------------
// LayerNorm (dim 256) -> bf16 output
// ---------------------------------------------------------------------------
__global__ __launch_bounds__(256) void ln_k(const float* __restrict__ f,
                                            const float* __restrict__ g,
                                            const float* __restrict__ b,
                                            unsigned short* __restrict__ xn) {
    int row = blockIdx.x * 4 + (threadIdx.x >> 6);
    int lane = threadIdx.x & 63;
    const float* xp = f + (size_t)row * 256;
    float4 v = *(const float4*)(xp + lane * 4);
    float s = v.x + v.y + v.z + v.w;
#pragma unroll
    for (int o = 32; o > 0; o >>= 1) s += __shfl_xor(s, o);
    float mean = s * (1.f / 256.f);
    float dx = v.x - mean, dy = v.y - mean, dz = v.z - mean, dw = v.w - mean;
    float ss = dx * dx + dy * dy + dz * dz + dw * dw;
#pragma unroll
    for (int o = 32; o > 0; o >>= 1) ss += __shfl_xor(ss, o);
    float rstd = rsqrtf(ss * (1.f / 256.f) + 1e-5f);
    float4 gg = *(const float4*)(g + lane * 4);
    float4 bb = *(const float4*)(b + lane * 4);
    ushort4 o4;
    o4.x = f2bf(dx * rstd * gg.x + bb.x);
    o4.y = f2bf(dy * rstd * gg.y + bb.y);
    o4.z = f2bf(dz * rstd * gg.z + bb.z);
    o4.w = f2bf(dw * rstd * gg.w + bb.w);
    *(ushort4*)(xn + (size_t)row * 256 + lane * 4) = o4;
}

// ---------------------------------------------------------------------------
// fp32 GEMM (kept for dt-proj, K=16): C = softplus(A@W^T + bias)
// ---------------------------------------------------------------------------
template <int BIAS, int ACT, int ACCUM>
__global__ __launch_bounds__(256) void gemm_tn(const float* __restrict__ A,
                                               const float* __restrict__ W,
                                               const float* __restrict__ bias,
                                               float* __restrict__ C,
                                               int M, int N, int K, int lda) {
    __shared__ float As[16][68];
    __shared__ float Ws[16][68];
    const int t = threadIdx.x;
    const int tx = t & 15;
    const int ty = t >> 4;
    const int rowBase = blockIdx.y * 64;
    const int colBase = blockIdx.x * 64;
    const int lRow = t >> 2;
    const int lK = (t & 3) * 4;
    float acc[4][4] = {};
    for (int k0 = 0; k0 < K; k0 += 16) {
        {
            const float* src = A + (size_t)(rowBase + lRow) * lda + k0 + lK;
            float4 v = *(const float4*)src;
            As[lK + 0][lRow] = v.x;
            As[lK + 1][lRow] = v.y;
            As[lK + 2][lRow] = v.z;
            As[lK + 3][lRow] = v.w;
        }
        {
            int n = colBase + lRow;
            float4 v = make_float4(0.f, 0.f, 0.f, 0.f);
            if (n < N) v = *(const float4*)(W + (size_t)n * K + k0 + lK);
            Ws[lK + 0][lRow] = v.x;
            Ws[lK + 1][lRow] = v.y;
            Ws[lK + 2][lRow] = v.z;
            Ws[lK + 3][lRow] = v.w;
        }
        __syncthreads();
#pragma unroll
        for (int kk = 0; kk < 16; ++kk) {
            float4 a4 = *(const float4*)&As[kk][ty * 4];
            float4 w4 = *(const float4*)&Ws[kk][tx * 4];
            float av[4] = {a4.x, a4.y, a4.z, a4.w};
            float wv[4] = {w4.x, w4.y, w4.z, w4.w};
#pragma unroll
            for (int i = 0; i < 4; ++i)
#pragma unroll
                for (int j = 0; j < 4; ++j)
                    acc[i][j] = fmaf(av[i], wv[j], acc[i][j]);
        }
        __syncthreads();
    }
#pragma unroll
    for (int i = 0; i < 4; ++i) {
        int row = rowBase + ty * 4 + i;
#pragma unroll
        for (int j = 0; j < 4; ++j) {
            int col = colBase + tx * 4 + j;
            if (col < N) {
                float v = acc[i][j];
                if (BIAS) v += bias[col];
                if (ACT == 1) v = (v > 20.f) ? v : log1pf(__expf(v));
                size_t idx = (size_t)row * N + col;
                if (ACCUM)
                    C[idx] += v;
                else
                    C[idx] = v;
            }
        }
    }
}

// ---------------------------------------------------------------------------
// Causal depthwise conv1d (k=4) + bias + SiLU -> bf16 only
// ---------------------------------------------------------------------------
__global__ __launch_bounds__(256) void dwconv_k(const float* __restrict__ xz,
                                                const float* __restrict__ cw,
                                                const float* __restrict__ cb,
                                                unsigned short* __restrict__ xcb) {
    int idx = blockIdx.x * 256 + threadIdx.x;  // 8*1024*512
    if (idx >= 8 * 1024 * 512) return;
    int d = idx & 511;
    int tt = (idx >> 9) & 1023;
    int b = idx >> 19;
    const float* xp = xz + (size_t)b * 1024 * 1024 + d;
    float w0 = cw[d * 4], w1 = cw[d * 4 + 1], w2 = cw[d * 4 + 2], w3 = cw[d * 4 + 3];
    float acc = cb[d];
    if (tt >= 3) acc = fmaf(xp[(size_t)(tt - 3) * 1024], w0, acc);
    if (tt >= 2) acc = fmaf(xp[(size_t)(tt - 2) * 1024], w1, acc);
    if (tt >= 1) acc = fmaf(xp[(size_t)(tt - 1) * 1024], w2, acc);
    acc = fmaf(xp[(size_t)tt * 1024], w3, acc);
    float v = acc / (1.f + __expf(-acc));
    xcb[idx] = f2bf(v);
}

// ---------------------------------------------------------------------------
// Selective scan v3. Block (16 ch, batch), 256 threads (s=tid&15, dl=tid>>4).
// - LDS transposed [ch][tt] (pad 68): b128 reads cover 4 steps, wave-broadcast.
// - s-reduction via DPP row_ror allreduce (VALU-only, no LDS round-trip).
// - lane s==tt&15 keeps step tt's sum; epilogue every 16 steps.
// - xv from bf16 xcb; y bf16.
// ---------------------------------------------------------------------------
__global__ __launch_bounds__(256) void scan_k(const float* __restrict__ dtb,
                                              const float* __restrict__ xdbl,
                                              const unsigned short* __restrict__ xcb,
                                              const float* __restrict__ A_log,
                                              const float* __restrict__ Dp,
                                              const float* __restrict__ xz,
                                              unsigned short* __restrict__ y) {
    __shared__ float dtT[2][16][68];
    __shared__ float xvT[2][16][68];
    __shared__ float BT[2][16][68];
    __shared__ float CT[2][16][68];
    __shared__ float zT[2][16][68];

    const int tid = threadIdx.x;
    const int s = tid & 15;
    const int dl = tid >> 4;          // 0..15
    const int d0 = blockIdx.x * 16;
    const int b = blockIdx.y;

    const float A = -__expf(A_log[(d0 + dl) * 16 + s]);
    const float DpV = Dp[d0 + dl];

    const int r4 = tid >> 2;          // staging tt 0..63
    const int c4 = (tid & 3) * 4;     // staging ch 0,4,8,12

    const size_t rowB = (size_t)b * 1024;
    const float* pdt = dtb + (rowB + r4) * 512 + d0 + c4;
    const unsigned short* pxv = xcb + (rowB + r4) * 512 + d0 + c4;
    const float* pB = xdbl + (rowB + r4) * 48 + 16 + c4;
    const float* pC = xdbl + (rowB + r4) * 48 + 32 + c4;
    const float* pz = xz + (rowB + r4) * 1024 + 512 + d0 + c4;

    float4 vdt = *(const float4*)pdt;
    ushort4 vxu = *(const ushort4*)pxv;
    float4 vB = *(const float4*)pB;
    float4 vC = *(const float4*)pC;
    float4 vz = *(const float4*)pz;

#define STAGE(buf)                                                                     \
    {                                                                                  \
        const float* ap = (const float*)&vdt;                                          \
        const unsigned short* xp_ = (const unsigned short*)&vxu;                       \
        const float* Bp = (const float*)&vB;                                           \
        const float* Cp = (const float*)&vC;                                           \
        const float* zp = (const float*)&vz;                                           \
        _Pragma("unroll") for (int i = 0; i < 4; ++i) {                                \
            dtT[buf][c4 + i][r4] = ap[i];                                              \
            xvT[buf][c4 + i][r4] = __uint_as_float((unsigned)xp_[i] << 16);            \
            BT[buf][c4 + i][r4] = Bp[i];                                               \
            CT[buf][c4 + i][r4] = Cp[i];                                               \
            zT[buf][c4 + i][r4] = zp[i];                                               \
        }                                                                              \
    }

    STAGE(0);
    __syncthreads();

    float h = 0.f;
    float ykeep = 0.f;
    for (int tile = 0; tile < 16; ++tile) {
        const int p = tile & 1;
        if (tile < 15) {
            size_t off = (size_t)(tile + 1) * 64;
            vdt = *(const float4*)(pdt + off * 512);
            vxu = *(const ushort4*)(pxv + off * 512);
            vB = *(const float4*)(pB + off * 48);
            vC = *(const float4*)(pC + off * 48);
            vz = *(const float4*)(pz + off * 1024);
        }
#pragma unroll
        for (int q4 = 0; q4 < 16; ++q4) {
            float4 dt4 = *(const float4*)&dtT[p][dl][q4 * 4];
            float4 xv4 = *(const float4*)&xvT[p][dl][q4 * 4];
            float4 B4 = *(const float4*)&BT[p][s][q4 * 4];
            float4 C4 = *(const float4*)&CT[p][s][q4 * 4];
            const float* dtp_ = (const float*)&dt4;
            const float* xvp_ = (const float*)&xv4;
            const float* Bp_ = (const float*)&B4;
            const float* Cp_ = (const float*)&C4;
#pragma unroll
            for (int j = 0; j < 4; ++j) {
                const int tt = q4 * 4 + j;
                float dt = dtp_[j];
                float dA = __expf(dt * A);
                h = fmaf(dA, h, dt * xvp_[j] * Bp_[j]);
                float pr = h * Cp_[j];
                pr = dpp_add<0x121>(pr);  // row_ror:1
                pr = dpp_add<0x122>(pr);  // row_ror:2
                pr = dpp_add<0x124>(pr);  // row_ror:4
                pr = dpp_add<0x128>(pr);  // row_ror:8
                if (s == (tt & 15)) ykeep = pr;
            }
            if ((q4 & 3) == 3) {
                const int sub = q4 >> 2;
                const int tte = sub * 16 + s;
                float xve = xvT[p][dl][tte];
                float ze = zT[p][dl][tte];
                float sg = ze / (1.f + __expf(-ze));
                float yv = (ykeep + DpV * xve) * sg;
                y[(rowB + tile * 64 + tte) * 512 + d0 + dl] = f2bf(yv);
            }
        }
        if (tile < 15) STAGE(p ^ 1);
        __syncthreads();
    }
#undef STAGE
}

// ---------------------------------------------------------------------------
// Adaptive avg-pool 32x32 -> 8x8 over (B, L, C) -> bf16 feat
// ---------------------------------------------------------------------------
__global__ __launch_bounds__(256) void pool_k(const float* __restrict__ f,
                                              unsigned short* __restrict__ feat) {
    int idx = blockIdx.x * 256 + threadIdx.x;  // 8*64*256
    if (idx >= 8 * 64 * 256) return;
    int ch = idx & 255;
    int rc = (idx >> 8) & 63;
    int b = idx >> 14;
    int r = rc >> 3, c = rc & 7;
    float s = 0.f;
#pragma unroll
    for (int i = 0; i < 4; ++i)
#pragma unroll
        for (int j = 0; j < 4; ++j) {
            int l = (r * 4 + i) * 32 + (c * 4 + j);
            s += f[((size_t)b * 1024 + l) * 256 + ch];
        }
    feat[idx] = f2bf(s * (1.f / 16.f));
}

// ---------------------------------------------------------------------------
// weight conversion helpers
// ---------------------------------------------------------------------------
__global__ __launch_bounds__(256) void cvt_k(const float* __restrict__ s,
                                             unsigned short* __restrict__ d, int n4) {
    int i = blockIdx.x * 256 + threadIdx.x;
    if (i >= n4) return;
    float4 v = *(const float4*)(s + (size_t)i * 4);
    ushort4 u;
    u.x = f2bf(v.x);
    u.y = f2bf(v.y);
    u.z = f2bf(v.z);
    u.w = f2bf(v.w);
    *(ushort4*)(d + (size_t)i * 4) = u;
}

// xp_w (4,48,512) -> (4,128,512) zero-padded bf16
__global__ __launch_bounds__(256) void xpw_pad_k(const float* __restrict__ s,
                                                 unsigned short* __restrict__ d) {
    int idx = blockIdx.x * 256 + threadIdx.x;  // 4*128*512
    if (idx >= 4 * 128 * 512) return;
    int l = idx >> 16;
    int n = (idx >> 9) & 127;
    int k = idx & 511;
    d[idx] = (n < 48) ? f2bf(s[((size_t)l * 48 + n) * 512 + k]) : (unsigned short)0;
}

// conv2_w (256,128,3,3) -> w2col (256, (r*3+c)*128+ic) bf16
__global__ __launch_bounds__(256) void w2col_k(const float* __restrict__ s,
                                               unsigned short* __restrict__ d) {
    int idx = blockIdx.x * 256 + threadIdx.x;  // 256*1152
    if (idx >= 256 * 1152) return;
    int oc = idx / 1152;
    int kk = idx % 1152;
    int r3c = kk >> 7;
    int ic = kk & 127;
    d[idx] = f2bf(s[((size_t)(oc * 128 + ic)) * 9 + r3c]);
}

// ---------------------------------------------------------------------------
// launch
// ---------------------------------------------------------------------------
extern "C" void kernel_launch(void* const* d_in, const int* in_sizes, int n_in,
                              void* d_out, int out_size, void* d_ws, size_t ws_size,
                              hipStream_t stream) {
    const float* x = (const float*)d_in[0];
    const float* conv1_w = (const float*)d_in[1];
    const float* conv1_b = (const float*)d_in[2];
    const float* gn1_g = (const float*)d_in[3];
    const float* gn1_b = (const float*)d_in[4];
    const float* conv2_w = (const float*)d_in[5];
    const float* conv2_b = (const float*)d_in[6];
    const float* gn2_g = (const float*)d_in[7];
    const float* gn2_b = (const float*)d_in[8];
    const float* ln_g = (const float*)d_in[9];
    const float* ln_b = (const float*)d_in[10];
    const float* in_w = (const float*)d_in[11];
    const float* cw = (const float*)d_in[12];
    const float* cb = (const float*)d_in[13];
    const float* xp_w = (const float*)d_in[14];
    const float* dtp_w = (const float*)d_in[15];
    const float* dtp_b = (const float*)d_in[16];
    const float* A_log = (const float*)d_in[17];
    const float* Dp = (const float*)d_in[18];
    const float* out_w = (const float*)d_in[19];
    const float* head_w = (const float*)d_in[20];
    const float* head_b = (const float*)d_in[21];
    float* out = (float*)d_out;

    char* ws = (char*)d_ws;
    float* f = (float*)(ws + 0);                         //  8,388,608
    float* xz = (float*)(ws + 8388608);                  // 33,554,432 (stem: h1 fp32 / imcol bf16)
    float* xc = (float*)(ws + 41943040);                 // 16,777,216 (tail: headw_b)
    float* xdbl = (float*)(ws + 58720256);               //  1,572,864 (tail: feat_b)
    float* dtb = (float*)(ws + 60293120);                // 16,777,216 (stem: h1nhwc bf16)
    unsigned short* xn_b = (unsigned short*)(ws + 77070336);    // 4,194,304
    unsigned short* xcb = (unsigned short*)(ws + 81264640);     // 8,388,608
    unsigned short* ybuf_b = (unsigned short*)(ws + 89653248);  // 8,388,608
    unsigned short* w2col_b = (unsigned short*)(ws + 98041856); //   589,824
    unsigned short* inw_b = (unsigned short*)(ws + 98631680);   // 2,097,152
    unsigned short* xpw_b = (unsigned short*)(ws + 100728832);  //   524,288
    unsigned short* outw_b = (unsigned short*)(ws + 101253120); // 1,048,576
    float* stats = (float*)(ws + 102301696);             // 512

    float* h1 = xz;                                      // stem alias
    unsigned short* h1n = (unsigned short*)dtb;          // stem alias
    unsigned short* imcol = (unsigned short*)xz;         // stem alias (after h1 dead)
    unsigned short* headw_b = (unsigned short*)xc;       // tail alias
    unsigned short* feat_b = (unsigned short*)xdbl;      // tail alias

    // ---- weight conversions ----
    w2col_k<<<(256 * 1152 + 255) / 256, 256, 0, stream>>>(conv2_w, w2col_b);
    cvt_k<<<(1048576 / 4 + 255) / 256, 256, 0, stream>>>(in_w, inw_b, 1048576 / 4);
    xpw_pad_k<<<(4 * 128 * 512 + 255) / 256, 256, 0, stream>>>(xp_w, xpw_b);
    cvt_k<<<(524288 / 4 + 255) / 256, 256, 0, stream>>>(out_w, outw_b, 524288 / 4);

    // ---- conv stem ----
    conv1_k<<<512, 256, 0, stream>>>(x, conv1_w, conv1_b, h1);
    gn_stats_k<<<64, 256, 0, stream>>>(h1, stats, 16, 4096);
    gn_apply_k<<<(8 * 128 * 64 * 64 + 255) / 256, 256, 0, stream>>>(h1, stats, gn1_g, gn1_b, 128, 16, 4096, 8 * 128 * 64 * 64);
    nhwc_k<<<512, 256, 0, stream>>>(h1, h1n);
    im2col_k<<<(8192 * 9 * 8 + 255) / 256, 256, 0, stream>>>(h1n, imcol);
    gemm_bf16<1, 0><<<dim3(2, 64), 256, 0, stream>>>(imcol, w2col_b, conv2_b, f, 1152, 256, 256);
    gn2_stats_nhwc_k<<<64, 256, 0, stream>>>(f, stats);
    gn2_apply_nhwc_k<<<(8 * 1024 * 256 + 255) / 256, 256, 0, stream>>>(f, stats, gn2_g, gn2_b);

    // ---- SSM layers ----
    for (int i = 0; i < N_LAYERS; ++i) {
        ln_k<<<2048, 256, 0, stream>>>(f, ln_g + i * 256, ln_b + i * 256, xn_b);
        gemm_bf16<0, 0><<<dim3(8, 64), 256, 0, stream>>>(
            xn_b, inw_b + (size_t)i * 1024 * 256, nullptr, xz, 256, 1024, 1024);
        dwconv_k<<<(8 * 1024 * 512 + 255) / 256, 256, 0, stream>>>(
            xz, cw + i * 512 * 4, cb + i * 512, xcb);
        gemm_bf16<0, 0><<<dim3(1, 64), 256, 0, stream>>>(
            xcb, xpw_b + (size_t)i * 128 * 512, nullptr, xdbl, 512, 48, 48);
        gemm_tn<1, 1, 0><<<dim3(8, 128), 256, 0, stream>>>(
            xdbl, dtp_w + (size_t)i * 512 * 16, dtp_b + i * 512, dtb, 8192, 512, 16, 48);
        scan_k<<<dim3(32, 8), 256, 0, stream>>>(
            dtb, xdbl, xcb, A_log + (size_t)i * 512 * 16, Dp + i * 512, xz, ybuf_b);
        gemm_bf16<0, 1><<<dim3(2, 64), 256, 0, stream>>>(
            ybuf_b, outw_b + (size_t)i * 256 * 512, nullptr, f, 512, 256, 256);
    }

    // ---- pool + heads ----
    cvt_k<<<(8388608 / 4 + 255) / 256, 256, 0, stream>>>(head_w, headw_b, 8388608 / 4);
    pool_k<<<(8 * 64 * 256 + 255) / 256, 256, 0, stream>>>(f, feat_b);
    for (int d = 0; d < N_DEPTHS; ++d) {
        gemm_bf16<1, 0><<<dim3(64, 4), 256, 0, stream>>>(
            feat_b, headw_b + (size_t)d * N_EMB * 256, head_b + (size_t)d * N_EMB,
            out + (size_t)d * BATCH * 64 * N_EMB, 256, N_EMB, N_EMB);
    }
}